// Round 10
// baseline (130.495 us; speedup 1.0000x reference)
//
#include <hip/hip_runtime.h>
#include <math.h>

#define HW 16384
#define CC 64
#define HID 128
#define EPSV 1e-5f
#define ROW 36     // padded LDS row for 32-pixel fp32 tiles
#define QROW 197   // padded per-pixel row for qkv fp32 staging (192 + 5, odd)
#define HDSTR 131072    // per-head stride: 32*32*16*8 floats

typedef __attribute__((ext_vector_type(8))) short bf16x8;   // 8 bf16 = 4 VGPRs
typedef __attribute__((ext_vector_type(4))) float f32x4v;   // MFMA accumulator

__device__ __forceinline__ unsigned short f2bf(float f) {   // RNE fp32->bf16
    unsigned u = __float_as_uint(f);
    u += 0x7FFFu + ((u >> 16) & 1u);
    return (unsigned short)(u >> 16);
}
__device__ __forceinline__ unsigned pack2bf(float a, float b) {
    return (unsigned)f2bf(a) | ((unsigned)f2bf(b) << 16);
}
__device__ __forceinline__ bf16x8 frag_from_f32(const float* p) {
    float4 wa = *(const float4*)p;
    float4 wb = *(const float4*)(p + 4);
    union { unsigned u[4]; bf16x8 v; } cvt;
    cvt.u[0] = pack2bf(wa.x, wa.y);
    cvt.u[1] = pack2bf(wa.z, wa.w);
    cvt.u[2] = pack2bf(wb.x, wb.y);
    cvt.u[3] = pack2bf(wb.z, wb.w);
    return cvt.v;
}

// q/k/v layout: [head][(hs*32+ws)*16 + sub][8], sub = (h&3)*4 + (w&3)

// ---------------- Kernel A: ln1 -> qkv via MFMA -> q/k LN -> ws ----------------
// Weight fragments loaded per-lane directly from global fp32 (L2-resident) and
// converted in registers — no LDS staging, loads overlap ln1 latency.
__global__ __launch_bounds__(256, 2) void k_ln_qkv(
    const float* __restrict__ x,
    const float* __restrict__ n1w, const float* __restrict__ n1b,
    const float* __restrict__ qkvw, const float* __restrict__ qkvb,
    const float* __restrict__ qnw, const float* __restrict__ qnb,
    const float* __restrict__ knw, const float* __restrict__ knb,
    float* __restrict__ qo, float* __restrict__ ko, float* __restrict__ vo)
{
    __shared__ __align__(16) float xs[CC][ROW];              // fp32 x tile [chan][px]
    __shared__ __align__(16) unsigned short xh[32][72];      // ln1(x) bf16 [px][chan]
    __shared__ __align__(16) float qk[32][QROW];             // qkv out fp32 [px][out]
    __shared__ __align__(16) float mu1[32], rs1[32], muq[32], rsq[32], muk[32], rsk[32];

    const int t = threadIdx.x;
    const int pix0 = blockIdx.x * 32;
    const int wv = t >> 6;      // wave 0..3
    const int l = t & 63;
    const int ln = l & 15;      // frag col (px) / A-row within 16-stripe
    const int kg = l >> 4;      // frag k-group

    {
        const int c = t >> 2, pxq = (t & 3) * 8;
        *(float4*)&xs[c][pxq]     = *(const float4*)(x + c * HW + pix0 + pxq);
        *(float4*)&xs[c][pxq + 4] = *(const float4*)(x + c * HW + pix0 + pxq + 4);
    }

    // per-lane weight fragments, issued early to overlap ln1 (no barrier dependency)
    bf16x8 wfrag[3][2];
    {
        const int mbase = wv * 48;
        #pragma unroll
        for (int mt = 0; mt < 3; ++mt) {
            const int row = mbase + mt * 16 + ln;
            #pragma unroll
            for (int kt2 = 0; kt2 < 2; ++kt2) {
                wfrag[mt][kt2] = frag_from_f32(qkvw + row * 64 + kt2 * 32 + kg * 8);
            }
        }
    }
    __syncthreads();

    if (t < 128) {
        const int px = ((t >> 6) << 4) + (t & 15);
        const int part = (t & 63) >> 4;
        float s = 0.f, ss = 0.f;
        #pragma unroll
        for (int i = 0; i < 16; ++i) { float v = xs[part * 16 + i][px]; s += v; ss += v * v; }
        s += __shfl_xor(s, 16); ss += __shfl_xor(ss, 16);
        s += __shfl_xor(s, 32); ss += __shfl_xor(ss, 32);
        if (part == 0) {
            float m = s * (1.f / CC);
            mu1[px] = m;
            rs1[px] = rsqrtf(ss * (1.f / CC) - m * m + EPSV);
        }
    }
    __syncthreads();

    {
        const int c2 = (t & 31) * 2, px0 = (t >> 5) * 4;
        const float w0 = n1w[c2], b0 = n1b[c2];
        const float w1 = n1w[c2 + 1], b1 = n1b[c2 + 1];
        float4 va = *(float4*)&xs[c2][px0];
        float4 vb = *(float4*)&xs[c2 + 1][px0];
        float4 m4 = *(float4*)&mu1[px0];
        float4 r4 = *(float4*)&rs1[px0];
        #pragma unroll
        for (int i = 0; i < 4; ++i) {
            float f0 = ((&va.x)[i] - (&m4.x)[i]) * (&r4.x)[i] * w0 + b0;
            float f1 = ((&vb.x)[i] - (&m4.x)[i]) * (&r4.x)[i] * w1 + b1;
            *(unsigned*)&xh[px0 + i][c2] = pack2bf(f0, f1);
        }
    }
    __syncthreads();

    {
        f32x4v acc[3][2];
        #pragma unroll
        for (int mt = 0; mt < 3; ++mt) {
            acc[mt][0] = (f32x4v){0.f, 0.f, 0.f, 0.f};
            acc[mt][1] = (f32x4v){0.f, 0.f, 0.f, 0.f};
        }
        const int mbase = wv * 48;
        #pragma unroll
        for (int kt2 = 0; kt2 < 2; ++kt2) {
            const int k0 = kt2 * 32 + kg * 8;
            bf16x8 b0 = *(const bf16x8*)&xh[ln][k0];
            bf16x8 b1 = *(const bf16x8*)&xh[16 + ln][k0];
            #pragma unroll
            for (int mt = 0; mt < 3; ++mt) {
                acc[mt][0] = __builtin_amdgcn_mfma_f32_16x16x32_bf16(wfrag[mt][kt2], b0, acc[mt][0], 0, 0, 0);
                acc[mt][1] = __builtin_amdgcn_mfma_f32_16x16x32_bf16(wfrag[mt][kt2], b1, acc[mt][1], 0, 0, 0);
            }
        }
        #pragma unroll
        for (int mt = 0; mt < 3; ++mt) {
            const int r0 = mbase + mt * 16 + kg * 4;
            float4 qb4 = *(const float4*)(qkvb + r0);
            #pragma unroll
            for (int reg = 0; reg < 4; ++reg) {
                qk[ln][r0 + reg]      = acc[mt][0][reg] + (&qb4.x)[reg];
                qk[16 + ln][r0 + reg] = acc[mt][1][reg] + (&qb4.x)[reg];
            }
        }
    }
    __syncthreads();

    if (t < 128) {
        const int px = ((t >> 6) << 4) + (t & 15);
        const int part = (t & 63) >> 4;
        float s = 0.f, ss = 0.f;
        #pragma unroll
        for (int i = 0; i < 16; ++i) { float v = qk[px][part * 16 + i]; s += v; ss += v * v; }
        s += __shfl_xor(s, 16); ss += __shfl_xor(ss, 16);
        s += __shfl_xor(s, 32); ss += __shfl_xor(ss, 32);
        if (part == 0) {
            float m = s * (1.f / CC);
            muq[px] = m;
            rsq[px] = rsqrtf(ss * (1.f / CC) - m * m + EPSV);
        }
    } else {
        const int t2 = t - 128;
        const int px = ((t2 >> 6) << 4) + (t2 & 15);
        const int part = (t2 & 63) >> 4;
        float s = 0.f, ss = 0.f;
        #pragma unroll
        for (int i = 0; i < 16; ++i) { float v = qk[px][CC + part * 16 + i]; s += v; ss += v * v; }
        s += __shfl_xor(s, 16); ss += __shfl_xor(ss, 16);
        s += __shfl_xor(s, 32); ss += __shfl_xor(ss, 32);
        if (part == 0) {
            float m = s * (1.f / CC);
            muk[px] = m;
            rsk[px] = rsqrtf(ss * (1.f / CC) - m * m + EPSV);
        }
    }
    __syncthreads();

    #pragma unroll
    for (int pass = 0; pass < 2; ++pass) {
        const int px = (t >> 4) + pass * 16;
        const int cg = t & 15;
        const int c = cg * 4;
        const int hd = cg >> 1;
        const int d4 = (cg & 1) * 4;
        const int pixel = pix0 + px;
        const int h = pixel >> 7, w = pixel & 127;
        const int pos = ((h >> 2) * 32 + (w >> 2)) * 16 + (h & 3) * 4 + (w & 3);
        const int gbase = hd * HDSTR + pos * 8 + d4;

        const float mq = muq[px], rq = rsq[px];
        float4 qv = *(float4*)&qk[px][c];
        float4 qw = *(const float4*)(qnw + c);
        float4 qb = *(const float4*)(qnb + c);
        qv.x = (qv.x - mq) * rq * qw.x + qb.x;
        qv.y = (qv.y - mq) * rq * qw.y + qb.y;
        qv.z = (qv.z - mq) * rq * qw.z + qb.z;
        qv.w = (qv.w - mq) * rq * qw.w + qb.w;
        *(float4*)(qo + gbase) = qv;

        const float mk = muk[px], rk = rsk[px];
        float4 kv = *(float4*)&qk[px][CC + c];
        float4 kw = *(const float4*)(knw + c);
        float4 kb = *(const float4*)(knb + c);
        kv.x = (kv.x - mk) * rk * kw.x + kb.x;
        kv.y = (kv.y - mk) * rk * kw.y + kb.y;
        kv.z = (kv.z - mk) * rk * kw.z + kb.z;
        kv.w = (kv.w - mk) * rk * kw.w + kb.w;
        *(float4*)(ko + gbase) = kv;

        float4 vv = *(float4*)&qk[px][2 * CC + c];
        *(float4*)(vo + gbase) = vv;
    }
}

// ---------------- Kernel B: NAT, 512 threads, neighbor-split 2-way + LDS merge ----------------
// oatt written as bf16 (identical rounding to C's previous read-side conversion).
__global__ __launch_bounds__(512, 4) void k_attn(
    const float* __restrict__ q, const float* __restrict__ k, const float* __restrict__ v,
    unsigned short* __restrict__ o,
    const float* __restrict__ pw, const float* __restrict__ f1w, const float* __restrict__ f2w,
    unsigned short* __restrict__ pwh, unsigned short* __restrict__ f1h,
    unsigned short* __restrict__ f2h)
{
    __shared__ __align__(16) float kt[4][15][33][2];
    __shared__ __align__(16) float vt[4][15][33][2];
    __shared__ __align__(16) float pm[2][256];
    __shared__ __align__(16) float pl[2][256];
    __shared__ __align__(16) float pacc[2][256][8];

    const int t = threadIdx.x;
    const int half = t >> 8;        // 0 or 1 (wave-uniform)
    const int tt = t & 255;
    const int band = blockIdx.x;
    const int sub  = blockIdx.y;
    const int head = blockIdx.z;
    const int hs0 = band * 8;

    // one-shot bf16 conversion of C's weights
    {
        const int gtid = ((blockIdx.z * 16 + blockIdx.y) * 4 + blockIdx.x) * 512 + t;
        if (gtid < 4096)        pwh[gtid] = f2bf(pw[gtid]);
        else if (gtid < 12288)  f1h[gtid - 4096] = f2bf(f1w[gtid - 4096]);
        else if (gtid < 20480)  f2h[gtid - 12288] = f2bf(f2w[gtid - 12288]);
    }

    const float* kb = k + head * HDSTR;
    const float* vb = v + head * HDSTR;

    for (int idx = t; idx < 960; idx += 512) {
        const int row = idx >> 6;
        const int rem = idx & 63;
        const int wsc = rem >> 1;
        const int dh = rem & 1;
        int gr = hs0 - 4 + row;
        gr = gr < 0 ? 0 : (gr > 31 ? 31 : gr);
        const int gaddr = ((gr * 32 + wsc) * 16 + sub) * 8 + dh * 4;
        const float4 kv4 = *(const float4*)(kb + gaddr);
        const float4 vv4 = *(const float4*)(vb + gaddr);
        const int dp = dh * 2;
        kt[dp][row][wsc][0] = kv4.x;     kt[dp][row][wsc][1] = kv4.y;
        kt[dp + 1][row][wsc][0] = kv4.z; kt[dp + 1][row][wsc][1] = kv4.w;
        vt[dp][row][wsc][0] = vv4.x;     vt[dp][row][wsc][1] = vv4.y;
        vt[dp + 1][row][wsc][0] = vv4.z; vt[dp + 1][row][wsc][1] = vv4.w;
    }

    const int r = tt >> 5;        // 0..7
    const int wsc = tt & 31;      // 0..31
    const int hs = hs0 + r;

    const float* qp = q + head * HDSTR + ((hs * 32 + wsc) * 16 + sub) * 8;
    const float4 q0 = *(const float4*)qp;
    const float4 q1 = *(const float4*)(qp + 4);
    const float scale = 0.35355339059327373f;   // 8^-0.5

    __syncthreads();

    // ---- pass 1: this half's 32 scores; 4-way parallel max ----
    float s[32];
    float mx0 = -1e30f, mx1 = -1e30f, mx2 = -1e30f, mx3 = -1e30f;
    #pragma unroll
    for (int ii = 0; ii < 4; ++ii) {
        const int i = half * 4 + ii;
        const int lr = r + i;
        const bool vh = (unsigned)(hs + i - 4) < 32u;
        #pragma unroll
        for (int j = 0; j < 8; ++j) {
            const int cs = wsc + j - 4;
            const bool valid = vh && ((unsigned)cs < 32u);
            const int cc = cs < 0 ? 0 : (cs > 31 ? 31 : cs);
            const float2 kA = *(const float2*)&kt[0][lr][cc][0];
            const float2 kB = *(const float2*)&kt[1][lr][cc][0];
            const float2 kC = *(const float2*)&kt[2][lr][cc][0];
            const float2 kD = *(const float2*)&kt[3][lr][cc][0];
            float sv = q0.x * kA.x + q0.y * kA.y + q0.z * kB.x + q0.w * kB.y
                     + q1.x * kC.x + q1.y * kC.y + q1.z * kD.x + q1.w * kD.y;
            sv *= scale;
            sv = valid ? sv : -INFINITY;
            s[ii * 8 + j] = sv;
            if ((j & 3) == 0)      mx0 = fmaxf(mx0, sv);
            else if ((j & 3) == 1) mx1 = fmaxf(mx1, sv);
            else if ((j & 3) == 2) mx2 = fmaxf(mx2, sv);
            else                   mx3 = fmaxf(mx3, sv);
        }
    }
    const float mxh = fmaxf(fmaxf(mx0, mx1), fmaxf(mx2, mx3));

    // ---- pass 2: exp + PV accumulate ----
    float l = 0.f;
    float a0 = 0.f, a1 = 0.f, a2 = 0.f, a3 = 0.f, a4 = 0.f, a5 = 0.f, a6 = 0.f, a7 = 0.f;
    #pragma unroll
    for (int ii = 0; ii < 4; ++ii) {
        const int i = half * 4 + ii;
        const int lr = r + i;
        #pragma unroll
        for (int j = 0; j < 8; ++j) {
            const int cs = wsc + j - 4;
            const int cc = cs < 0 ? 0 : (cs > 31 ? 31 : cs);
            const float p = __expf(s[ii * 8 + j] - mxh);
            const float2 vA = *(const float2*)&vt[0][lr][cc][0];
            const float2 vB = *(const float2*)&vt[1][lr][cc][0];
            const float2 vC = *(const float2*)&vt[2][lr][cc][0];
            const float2 vD = *(const float2*)&vt[3][lr][cc][0];
            l += p;
            a0 += p * vA.x;  a1 += p * vA.y;
            a2 += p * vB.x;  a3 += p * vB.y;
            a4 += p * vC.x;  a5 += p * vC.y;
            a6 += p * vD.x;  a7 += p * vD.y;
        }
    }

    // ---- publish partials, merge across halves ----
    pm[half][tt] = mxh;
    pl[half][tt] = l;
    float4 own0 = {a0, a1, a2, a3};
    float4 own1 = {a4, a5, a6, a7};
    *(float4*)&pacc[half][tt][0] = own0;
    *(float4*)&pacc[half][tt][4] = own1;
    __syncthreads();

    const int oth = half ^ 1;
    const float m_o = pm[oth][tt];
    const float l_o = pl[oth][tt];
    const float4 po = (half == 0) ? *(const float4*)&pacc[oth][tt][0]
                                  : *(const float4*)&pacc[oth][tt][4];
    const float4 ow = (half == 0) ? own0 : own1;

    const float M = fmaxf(mxh, m_o);
    const float eo = __expf(mxh - M);
    const float eh = __expf(m_o - M);
    const float inv = 1.f / (l * eo + l_o * eh);

    const int a = sub >> 2, b = sub & 3;
    const int h = hs * 4 + a, w = wsc * 4 + b;
    unsigned short* op = o + (h * 128 + w) * 64 + head * 8 + half * 4;
    float rx = (ow.x * eo + po.x * eh) * inv;
    float ry = (ow.y * eo + po.y * eh) * inv;
    float rz = (ow.z * eo + po.z * eh) * inv;
    float rw = (ow.w * eo + po.w * eh) * inv;
    uint2 packed = {pack2bf(rx, ry), pack2bf(rz, rw)};
    *(uint2*)op = packed;
}

// ---------------- Kernel C: MFMA proj/fc1/fc2 + VALU LayerNorms ----------------
// oatt arrives pre-converted bf16 -> direct uint2 copy into LDS oh.
__global__ __launch_bounds__(256) void k_mlp(
    const float* __restrict__ x, const unsigned short* __restrict__ oatt,
    const unsigned short* __restrict__ pwh, const float* __restrict__ pb,
    const float* __restrict__ g1,
    const float* __restrict__ n2w, const float* __restrict__ n2b,
    const unsigned short* __restrict__ f1h, const float* __restrict__ f1b,
    const float* __restrict__ mnw, const float* __restrict__ mnb,
    const unsigned short* __restrict__ f2h, const float* __restrict__ f2b,
    const float* __restrict__ g2,
    float* __restrict__ out)
{
    __shared__ __align__(16) float xres[CC][ROW];
    __shared__ __align__(16) unsigned short oh[32][72];
    __shared__ __align__(16) unsigned short tbh[32][72];
    __shared__ __align__(16) float h1[HID][ROW];
    __shared__ __align__(16) unsigned short h1h[32][136];
    __shared__ __align__(16) float mu[32], rs[32];

    const int t = threadIdx.x;
    const int pix0 = blockIdx.x * 32;
    const int wv = t >> 6;
    const int l = t & 63;
    const int ln = l & 15;
    const int kg = l >> 4;

    {
        const int c = t >> 2, pxq = (t & 3) * 8;
        *(float4*)&xres[c][pxq]     = *(const float4*)(x + c * HW + pix0 + pxq);
        *(float4*)&xres[c][pxq + 4] = *(const float4*)(x + c * HW + pix0 + pxq + 4);
    }
    #pragma unroll
    for (int pass = 0; pass < 2; ++pass) {
        const int px = (t >> 4) + pass * 16, cg = (t & 15) * 4;
        uint2 ov = *(const uint2*)(oatt + (pix0 + px) * CC + cg);
        *(unsigned*)&oh[px][cg]     = ov.x;
        *(unsigned*)&oh[px][cg + 2] = ov.y;
    }
    __syncthreads();

    {
        f32x4v acc0 = {0.f, 0.f, 0.f, 0.f}, acc1 = {0.f, 0.f, 0.f, 0.f};
        const int m = wv * 16 + ln;
        #pragma unroll
        for (int kk = 0; kk < 64; kk += 32) {
            const int k0 = kk + kg * 8;
            bf16x8 av = *(const bf16x8*)(pwh + m * 64 + k0);
            bf16x8 b0 = *(const bf16x8*)&oh[ln][k0];
            bf16x8 b1 = *(const bf16x8*)&oh[16 + ln][k0];
            acc0 = __builtin_amdgcn_mfma_f32_16x16x32_bf16(av, b0, acc0, 0, 0, 0);
            acc1 = __builtin_amdgcn_mfma_f32_16x16x32_bf16(av, b1, acc1, 0, 0, 0);
        }
        const int r0 = wv * 16 + kg * 4;
        float4 pb4 = *(const float4*)(pb + r0);
        float4 g14 = *(const float4*)(g1 + r0);
        #pragma unroll
        for (int reg = 0; reg < 4; ++reg) {
            const int row = r0 + reg;
            xres[row][ln]      += (&g14.x)[reg] * (acc0[reg] + (&pb4.x)[reg]);
            xres[row][16 + ln] += (&g14.x)[reg] * (acc1[reg] + (&pb4.x)[reg]);
        }
    }
    __syncthreads();

    if (t < 128) {
        const int px = ((t >> 6) << 4) + (t & 15);
        const int part = (t & 63) >> 4;
        float s = 0.f, ss = 0.f;
        #pragma unroll
        for (int i = 0; i < 16; ++i) { float v = xres[part * 16 + i][px]; s += v; ss += v * v; }
        s += __shfl_xor(s, 16); ss += __shfl_xor(ss, 16);
        s += __shfl_xor(s, 32); ss += __shfl_xor(ss, 32);
        if (part == 0) {
            float m = s * (1.f / CC);
            mu[px] = m;
            rs[px] = rsqrtf(ss * (1.f / CC) - m * m + EPSV);
        }
    }
    __syncthreads();

    {
        const int c2 = (t & 31) * 2, px0 = (t >> 5) * 4;
        const float w0 = n2w[c2], b0 = n2b[c2];
        const float w1 = n2w[c2 + 1], b1 = n2b[c2 + 1];
        float4 va = *(float4*)&xres[c2][px0];
        float4 vb = *(float4*)&xres[c2 + 1][px0];
        float4 m4 = *(float4*)&mu[px0];
        float4 r4 = *(float4*)&rs[px0];
        #pragma unroll
        for (int i = 0; i < 4; ++i) {
            float f0 = ((&va.x)[i] - (&m4.x)[i]) * (&r4.x)[i] * w0 + b0;
            float f1 = ((&vb.x)[i] - (&m4.x)[i]) * (&r4.x)[i] * w1 + b1;
            *(unsigned*)&tbh[px0 + i][c2] = pack2bf(f0, f1);
        }
    }
    __syncthreads();

    {
        f32x4v a00 = {0.f,0.f,0.f,0.f}, a01 = {0.f,0.f,0.f,0.f};
        f32x4v a10 = {0.f,0.f,0.f,0.f}, a11 = {0.f,0.f,0.f,0.f};
        const int m0 = wv * 32 + ln;
        #pragma unroll
        for (int kk = 0; kk < 64; kk += 32) {
            const int k0 = kk + kg * 8;
            bf16x8 av0 = *(const bf16x8*)(f1h + m0 * 64 + k0);
            bf16x8 av1 = *(const bf16x8*)(f1h + (m0 + 16) * 64 + k0);
            bf16x8 b0 = *(const bf16x8*)&tbh[ln][k0];
            bf16x8 b1 = *(const bf16x8*)&tbh[16 + ln][k0];
            a00 = __builtin_amdgcn_mfma_f32_16x16x32_bf16(av0, b0, a00, 0, 0, 0);
            a01 = __builtin_amdgcn_mfma_f32_16x16x32_bf16(av0, b1, a01, 0, 0, 0);
            a10 = __builtin_amdgcn_mfma_f32_16x16x32_bf16(av1, b0, a10, 0, 0, 0);
            a11 = __builtin_amdgcn_mfma_f32_16x16x32_bf16(av1, b1, a11, 0, 0, 0);
        }
        const int r0 = wv * 32 + kg * 4;
        float4 fb0 = *(const float4*)(f1b + r0);
        float4 fb1 = *(const float4*)(f1b + r0 + 16);
        #pragma unroll
        for (int reg = 0; reg < 4; ++reg) {
            h1[r0 + reg][ln]           = a00[reg] + (&fb0.x)[reg];
            h1[r0 + reg][16 + ln]      = a01[reg] + (&fb0.x)[reg];
            h1[r0 + 16 + reg][ln]      = a10[reg] + (&fb1.x)[reg];
            h1[r0 + 16 + reg][16 + ln] = a11[reg] + (&fb1.x)[reg];
        }
    }
    __syncthreads();

    if (t < 128) {
        const int px = ((t >> 6) << 4) + (t & 15);
        const int part = (t & 63) >> 4;
        float s = 0.f, ss = 0.f;
        #pragma unroll
        for (int i = 0; i < 32; ++i) { float v = h1[part * 32 + i][px]; s += v; ss += v * v; }
        s += __shfl_xor(s, 16); ss += __shfl_xor(ss, 16);
        s += __shfl_xor(s, 32); ss += __shfl_xor(ss, 32);
        if (part == 0) {
            float m = s * (1.f / HID);
            mu[px] = m;
            rs[px] = rsqrtf(ss * (1.f / HID) - m * m + EPSV);
        }
    }
    __syncthreads();

    {
        const int c2 = (t & 63) * 2, pxm = (t >> 6) * 8;
        const float w0 = mnw[c2], b0 = mnb[c2];
        const float w1 = mnw[c2 + 1], b1 = mnb[c2 + 1];
        #pragma unroll
        for (int qq = 0; qq < 2; ++qq) {
            float4 va = *(float4*)&h1[c2][pxm + qq * 4];
            float4 vb = *(float4*)&h1[c2 + 1][pxm + qq * 4];
            float4 m4 = *(float4*)&mu[pxm + qq * 4];
            float4 r4 = *(float4*)&rs[pxm + qq * 4];
            #pragma unroll
            for (int i = 0; i < 4; ++i) {
                float h0 = ((&va.x)[i] - (&m4.x)[i]) * (&r4.x)[i] * w0 + b0;
                float h1v = ((&vb.x)[i] - (&m4.x)[i]) * (&r4.x)[i] * w1 + b1;
                h0 = h0 / (1.f + __expf(-h0));
                h1v = h1v / (1.f + __expf(-h1v));
                *(unsigned*)&h1h[pxm + qq * 4 + i][c2] = pack2bf(h0, h1v);
            }
        }
    }
    __syncthreads();

    {
        f32x4v acc0 = {0.f, 0.f, 0.f, 0.f}, acc1 = {0.f, 0.f, 0.f, 0.f};
        const int m = wv * 16 + ln;
        #pragma unroll
        for (int kk = 0; kk < 128; kk += 32) {
            const int k0 = kk + kg * 8;
            bf16x8 av = *(const bf16x8*)(f2h + m * 128 + k0);
            bf16x8 b0 = *(const bf16x8*)&h1h[ln][k0];
            bf16x8 b1 = *(const bf16x8*)&h1h[16 + ln][k0];
            acc0 = __builtin_amdgcn_mfma_f32_16x16x32_bf16(av, b0, acc0, 0, 0, 0);
            acc1 = __builtin_amdgcn_mfma_f32_16x16x32_bf16(av, b1, acc1, 0, 0, 0);
        }
        const int r0 = wv * 16 + kg * 4;
        float4 fb4 = *(const float4*)(f2b + r0);
        float4 g24 = *(const float4*)(g2 + r0);
        #pragma unroll
        for (int reg = 0; reg < 4; ++reg) {
            const int row = r0 + reg;
            out[row * HW + pix0 + ln]      = xres[row][ln]
                                           + (&g24.x)[reg] * (acc0[reg] + (&fb4.x)[reg]);
            out[row * HW + pix0 + 16 + ln] = xres[row][16 + ln]
                                           + (&g24.x)[reg] * (acc1[reg] + (&fb4.x)[reg]);
        }
    }
}

extern "C" void kernel_launch(void* const* d_in, const int* in_sizes, int n_in,
                              void* d_out, int out_size, void* d_ws, size_t ws_size,
                              hipStream_t stream) {
    (void)in_sizes; (void)n_in; (void)out_size; (void)ws_size;
    const float* x      = (const float*)d_in[0];
    const float* n1w    = (const float*)d_in[1];
    const float* n1b    = (const float*)d_in[2];
    const float* qkvw   = (const float*)d_in[3];
    const float* qkvb   = (const float*)d_in[4];
    const float* qnw    = (const float*)d_in[5];
    const float* qnb    = (const float*)d_in[6];
    const float* knw    = (const float*)d_in[7];
    const float* knb    = (const float*)d_in[8];
    const float* pw     = (const float*)d_in[9];
    const float* pb     = (const float*)d_in[10];
    const float* g1     = (const float*)d_in[11];
    const float* n2w    = (const float*)d_in[12];
    const float* n2b    = (const float*)d_in[13];
    const float* f1w    = (const float*)d_in[14];
    const float* f1b    = (const float*)d_in[15];
    const float* mnw    = (const float*)d_in[16];
    const float* mnb    = (const float*)d_in[17];
    const float* f2w    = (const float*)d_in[18];
    const float* f2b    = (const float*)d_in[19];
    const float* g2     = (const float*)d_in[20];
    float* out = (float*)d_out;

    float* ws = (float*)d_ws;
    const size_t CHW = (size_t)CC * HW;   // 1,048,576 floats
    float* qo   = ws;
    float* ko   = ws + CHW;
    float* vo   = ws + 2 * CHW;
    unsigned short* oatt = (unsigned short*)(ws + 3 * CHW);   // bf16, uses half the slot
    unsigned short* wsh = (unsigned short*)(ws + 4 * CHW);
    unsigned short* pwh = wsh;            // 4096
    unsigned short* f1h = wsh + 4096;     // 8192
    unsigned short* f2h = wsh + 12288;    // 8192

    k_ln_qkv<<<dim3(HW / 32), dim3(256), 0, stream>>>(
        x, n1w, n1b, qkvw, qkvb, qnw, qnb, knw, knb, qo, ko, vo);
    k_attn<<<dim3(4, 16, 8), dim3(512), 0, stream>>>(
        qo, ko, vo, oatt, pw, f1w, f2w, pwh, f1h, f2h);
    k_mlp<<<dim3(HW / 32), dim3(256), 0, stream>>>(
        x, oatt, pwh, pb, g1, n2w, n2b, f1h, f1b, mnw, mnb, f2h, f2b, g2, out);
}

// Round 11
// 129.723 us; speedup vs baseline: 1.0059x; 1.0059x over previous
//
#include <hip/hip_runtime.h>
#include <math.h>

#define HW 16384
#define CC 64
#define HID 128
#define EPSV 1e-5f
#define ROW 36     // padded LDS row for 32-pixel fp32 tiles
#define QROW 197   // padded per-pixel row for qkv fp32 staging (192 + 5, odd)
#define HDSTR 131072    // per-head stride: 32*32*16*8 floats

typedef __attribute__((ext_vector_type(8))) short bf16x8;   // 8 bf16 = 4 VGPRs
typedef __attribute__((ext_vector_type(4))) float f32x4v;   // MFMA accumulator

__device__ __forceinline__ unsigned short f2bf(float f) {   // RNE fp32->bf16
    unsigned u = __float_as_uint(f);
    u += 0x7FFFu + ((u >> 16) & 1u);
    return (unsigned short)(u >> 16);
}
__device__ __forceinline__ unsigned pack2bf(float a, float b) {
    return (unsigned)f2bf(a) | ((unsigned)f2bf(b) << 16);
}

// q/k/v layout: [head][(hs*32+ws)*16 + sub][8], sub = (h&3)*4 + (w&3)

// ---------------- Kernel A: ln1 -> qkv via MFMA -> q/k LN -> ws (r8-verified) ----------------
// Weights staged coalesced into LDS (wh) then read as fragments — r10's per-lane
// register-fragment variant regressed (strided global loads, 16x32B @ 256B stride).
__global__ __launch_bounds__(256) void k_ln_qkv(
    const float* __restrict__ x,
    const float* __restrict__ n1w, const float* __restrict__ n1b,
    const float* __restrict__ qkvw, const float* __restrict__ qkvb,
    const float* __restrict__ qnw, const float* __restrict__ qnb,
    const float* __restrict__ knw, const float* __restrict__ knb,
    float* __restrict__ qo, float* __restrict__ ko, float* __restrict__ vo)
{
    __shared__ __align__(16) float xs[CC][ROW];              // fp32 x tile [chan][px]
    __shared__ __align__(16) unsigned short xh[32][72];      // ln1(x) bf16 [px][chan]
    __shared__ __align__(16) unsigned short wh[192][72];     // qkvw bf16 [out][k]
    __shared__ __align__(16) float qk[32][QROW];             // qkv out fp32 [px][out]
    __shared__ __align__(16) float mu1[32], rs1[32], muq[32], rsq[32], muk[32], rsk[32];

    const int t = threadIdx.x;
    const int pix0 = blockIdx.x * 32;
    const int wv = t >> 6;      // wave 0..3
    const int l = t & 63;
    const int ln = l & 15;      // frag col (px) / A-row within 16-stripe
    const int kg = l >> 4;      // frag k-group

    {
        const int c = t >> 2, pxq = (t & 3) * 8;
        *(float4*)&xs[c][pxq]     = *(const float4*)(x + c * HW + pix0 + pxq);
        *(float4*)&xs[c][pxq + 4] = *(const float4*)(x + c * HW + pix0 + pxq + 4);
    }
    #pragma unroll
    for (int i = 0; i < 12; ++i) {
        const int f = i * 256 + t;
        const int row = f >> 4;
        const int k4 = (f & 15) * 4;
        float4 wv4 = *(const float4*)(qkvw + row * 64 + k4);
        *(unsigned*)&wh[row][k4]     = pack2bf(wv4.x, wv4.y);
        *(unsigned*)&wh[row][k4 + 2] = pack2bf(wv4.z, wv4.w);
    }
    __syncthreads();

    if (t < 128) {
        const int px = ((t >> 6) << 4) + (t & 15);
        const int part = (t & 63) >> 4;
        float s = 0.f, ss = 0.f;
        #pragma unroll
        for (int i = 0; i < 16; ++i) { float v = xs[part * 16 + i][px]; s += v; ss += v * v; }
        s += __shfl_xor(s, 16); ss += __shfl_xor(ss, 16);
        s += __shfl_xor(s, 32); ss += __shfl_xor(ss, 32);
        if (part == 0) {
            float m = s * (1.f / CC);
            mu1[px] = m;
            rs1[px] = rsqrtf(ss * (1.f / CC) - m * m + EPSV);
        }
    }
    __syncthreads();

    {
        const int c2 = (t & 31) * 2, px0 = (t >> 5) * 4;
        const float w0 = n1w[c2], b0 = n1b[c2];
        const float w1 = n1w[c2 + 1], b1 = n1b[c2 + 1];
        float4 va = *(float4*)&xs[c2][px0];
        float4 vb = *(float4*)&xs[c2 + 1][px0];
        float4 m4 = *(float4*)&mu1[px0];
        float4 r4 = *(float4*)&rs1[px0];
        #pragma unroll
        for (int i = 0; i < 4; ++i) {
            float f0 = ((&va.x)[i] - (&m4.x)[i]) * (&r4.x)[i] * w0 + b0;
            float f1 = ((&vb.x)[i] - (&m4.x)[i]) * (&r4.x)[i] * w1 + b1;
            *(unsigned*)&xh[px0 + i][c2] = pack2bf(f0, f1);
        }
    }
    __syncthreads();

    {
        f32x4v acc[3][2];
        #pragma unroll
        for (int mt = 0; mt < 3; ++mt) {
            acc[mt][0] = (f32x4v){0.f, 0.f, 0.f, 0.f};
            acc[mt][1] = (f32x4v){0.f, 0.f, 0.f, 0.f};
        }
        const int mbase = wv * 48;
        #pragma unroll
        for (int kk = 0; kk < 64; kk += 32) {
            const int k0 = kk + kg * 8;
            bf16x8 b0 = *(const bf16x8*)&xh[ln][k0];
            bf16x8 b1 = *(const bf16x8*)&xh[16 + ln][k0];
            #pragma unroll
            for (int mt = 0; mt < 3; ++mt) {
                bf16x8 av = *(const bf16x8*)&wh[mbase + mt * 16 + ln][k0];
                acc[mt][0] = __builtin_amdgcn_mfma_f32_16x16x32_bf16(av, b0, acc[mt][0], 0, 0, 0);
                acc[mt][1] = __builtin_amdgcn_mfma_f32_16x16x32_bf16(av, b1, acc[mt][1], 0, 0, 0);
            }
        }
        #pragma unroll
        for (int mt = 0; mt < 3; ++mt) {
            const int r0 = mbase + mt * 16 + kg * 4;
            float4 qb4 = *(const float4*)(qkvb + r0);
            #pragma unroll
            for (int reg = 0; reg < 4; ++reg) {
                qk[ln][r0 + reg]      = acc[mt][0][reg] + (&qb4.x)[reg];
                qk[16 + ln][r0 + reg] = acc[mt][1][reg] + (&qb4.x)[reg];
            }
        }
    }
    __syncthreads();

    if (t < 128) {
        const int px = ((t >> 6) << 4) + (t & 15);
        const int part = (t & 63) >> 4;
        float s = 0.f, ss = 0.f;
        #pragma unroll
        for (int i = 0; i < 16; ++i) { float v = qk[px][part * 16 + i]; s += v; ss += v * v; }
        s += __shfl_xor(s, 16); ss += __shfl_xor(ss, 16);
        s += __shfl_xor(s, 32); ss += __shfl_xor(ss, 32);
        if (part == 0) {
            float m = s * (1.f / CC);
            muq[px] = m;
            rsq[px] = rsqrtf(ss * (1.f / CC) - m * m + EPSV);
        }
    } else {
        const int t2 = t - 128;
        const int px = ((t2 >> 6) << 4) + (t2 & 15);
        const int part = (t2 & 63) >> 4;
        float s = 0.f, ss = 0.f;
        #pragma unroll
        for (int i = 0; i < 16; ++i) { float v = qk[px][CC + part * 16 + i]; s += v; ss += v * v; }
        s += __shfl_xor(s, 16); ss += __shfl_xor(ss, 16);
        s += __shfl_xor(s, 32); ss += __shfl_xor(ss, 32);
        if (part == 0) {
            float m = s * (1.f / CC);
            muk[px] = m;
            rsk[px] = rsqrtf(ss * (1.f / CC) - m * m + EPSV);
        }
    }
    __syncthreads();

    #pragma unroll
    for (int pass = 0; pass < 2; ++pass) {
        const int px = (t >> 4) + pass * 16;
        const int cg = t & 15;
        const int c = cg * 4;
        const int hd = cg >> 1;
        const int d4 = (cg & 1) * 4;
        const int pixel = pix0 + px;
        const int h = pixel >> 7, w = pixel & 127;
        const int pos = ((h >> 2) * 32 + (w >> 2)) * 16 + (h & 3) * 4 + (w & 3);
        const int gbase = hd * HDSTR + pos * 8 + d4;

        const float mq = muq[px], rq = rsq[px];
        float4 qv = *(float4*)&qk[px][c];
        float4 qw = *(const float4*)(qnw + c);
        float4 qb = *(const float4*)(qnb + c);
        qv.x = (qv.x - mq) * rq * qw.x + qb.x;
        qv.y = (qv.y - mq) * rq * qw.y + qb.y;
        qv.z = (qv.z - mq) * rq * qw.z + qb.z;
        qv.w = (qv.w - mq) * rq * qw.w + qb.w;
        *(float4*)(qo + gbase) = qv;

        const float mk = muk[px], rk = rsk[px];
        float4 kv = *(float4*)&qk[px][CC + c];
        float4 kw = *(const float4*)(knw + c);
        float4 kb = *(const float4*)(knb + c);
        kv.x = (kv.x - mk) * rk * kw.x + kb.x;
        kv.y = (kv.y - mk) * rk * kw.y + kb.y;
        kv.z = (kv.z - mk) * rk * kw.z + kb.z;
        kv.w = (kv.w - mk) * rk * kw.w + kb.w;
        *(float4*)(ko + gbase) = kv;

        float4 vv = *(float4*)&qk[px][2 * CC + c];
        *(float4*)(vo + gbase) = vv;
    }
}

// ---------------- Kernel B: NAT, 512 threads, neighbor-split 2-way + LDS merge ----------------
// oatt written as bf16 (identical rounding to C's previous read-side conversion).
__global__ __launch_bounds__(512, 4) void k_attn(
    const float* __restrict__ q, const float* __restrict__ k, const float* __restrict__ v,
    unsigned short* __restrict__ o,
    const float* __restrict__ pw, const float* __restrict__ f1w, const float* __restrict__ f2w,
    unsigned short* __restrict__ pwh, unsigned short* __restrict__ f1h,
    unsigned short* __restrict__ f2h)
{
    __shared__ __align__(16) float kt[4][15][33][2];
    __shared__ __align__(16) float vt[4][15][33][2];
    __shared__ __align__(16) float pm[2][256];
    __shared__ __align__(16) float pl[2][256];
    __shared__ __align__(16) float pacc[2][256][8];

    const int t = threadIdx.x;
    const int half = t >> 8;        // 0 or 1 (wave-uniform)
    const int tt = t & 255;
    const int band = blockIdx.x;
    const int sub  = blockIdx.y;
    const int head = blockIdx.z;
    const int hs0 = band * 8;

    // one-shot bf16 conversion of C's weights
    {
        const int gtid = ((blockIdx.z * 16 + blockIdx.y) * 4 + blockIdx.x) * 512 + t;
        if (gtid < 4096)        pwh[gtid] = f2bf(pw[gtid]);
        else if (gtid < 12288)  f1h[gtid - 4096] = f2bf(f1w[gtid - 4096]);
        else if (gtid < 20480)  f2h[gtid - 12288] = f2bf(f2w[gtid - 12288]);
    }

    const float* kb = k + head * HDSTR;
    const float* vb = v + head * HDSTR;

    for (int idx = t; idx < 960; idx += 512) {
        const int row = idx >> 6;
        const int rem = idx & 63;
        const int wsc = rem >> 1;
        const int dh = rem & 1;
        int gr = hs0 - 4 + row;
        gr = gr < 0 ? 0 : (gr > 31 ? 31 : gr);
        const int gaddr = ((gr * 32 + wsc) * 16 + sub) * 8 + dh * 4;
        const float4 kv4 = *(const float4*)(kb + gaddr);
        const float4 vv4 = *(const float4*)(vb + gaddr);
        const int dp = dh * 2;
        kt[dp][row][wsc][0] = kv4.x;     kt[dp][row][wsc][1] = kv4.y;
        kt[dp + 1][row][wsc][0] = kv4.z; kt[dp + 1][row][wsc][1] = kv4.w;
        vt[dp][row][wsc][0] = vv4.x;     vt[dp][row][wsc][1] = vv4.y;
        vt[dp + 1][row][wsc][0] = vv4.z; vt[dp + 1][row][wsc][1] = vv4.w;
    }

    const int r = tt >> 5;        // 0..7
    const int wsc = tt & 31;      // 0..31
    const int hs = hs0 + r;

    const float* qp = q + head * HDSTR + ((hs * 32 + wsc) * 16 + sub) * 8;
    const float4 q0 = *(const float4*)qp;
    const float4 q1 = *(const float4*)(qp + 4);
    const float scale = 0.35355339059327373f;   // 8^-0.5

    __syncthreads();

    // ---- pass 1: this half's 32 scores; 4-way parallel max ----
    float s[32];
    float mx0 = -1e30f, mx1 = -1e30f, mx2 = -1e30f, mx3 = -1e30f;
    #pragma unroll
    for (int ii = 0; ii < 4; ++ii) {
        const int i = half * 4 + ii;
        const int lr = r + i;
        const bool vh = (unsigned)(hs + i - 4) < 32u;
        #pragma unroll
        for (int j = 0; j < 8; ++j) {
            const int cs = wsc + j - 4;
            const bool valid = vh && ((unsigned)cs < 32u);
            const int cc = cs < 0 ? 0 : (cs > 31 ? 31 : cs);
            const float2 kA = *(const float2*)&kt[0][lr][cc][0];
            const float2 kB = *(const float2*)&kt[1][lr][cc][0];
            const float2 kC = *(const float2*)&kt[2][lr][cc][0];
            const float2 kD = *(const float2*)&kt[3][lr][cc][0];
            float sv = q0.x * kA.x + q0.y * kA.y + q0.z * kB.x + q0.w * kB.y
                     + q1.x * kC.x + q1.y * kC.y + q1.z * kD.x + q1.w * kD.y;
            sv *= scale;
            sv = valid ? sv : -INFINITY;
            s[ii * 8 + j] = sv;
            if ((j & 3) == 0)      mx0 = fmaxf(mx0, sv);
            else if ((j & 3) == 1) mx1 = fmaxf(mx1, sv);
            else if ((j & 3) == 2) mx2 = fmaxf(mx2, sv);
            else                   mx3 = fmaxf(mx3, sv);
        }
    }
    const float mxh = fmaxf(fmaxf(mx0, mx1), fmaxf(mx2, mx3));

    // ---- pass 2: exp + PV accumulate ----
    float l = 0.f;
    float a0 = 0.f, a1 = 0.f, a2 = 0.f, a3 = 0.f, a4 = 0.f, a5 = 0.f, a6 = 0.f, a7 = 0.f;
    #pragma unroll
    for (int ii = 0; ii < 4; ++ii) {
        const int i = half * 4 + ii;
        const int lr = r + i;
        #pragma unroll
        for (int j = 0; j < 8; ++j) {
            const int cs = wsc + j - 4;
            const int cc = cs < 0 ? 0 : (cs > 31 ? 31 : cs);
            const float p = __expf(s[ii * 8 + j] - mxh);
            const float2 vA = *(const float2*)&vt[0][lr][cc][0];
            const float2 vB = *(const float2*)&vt[1][lr][cc][0];
            const float2 vC = *(const float2*)&vt[2][lr][cc][0];
            const float2 vD = *(const float2*)&vt[3][lr][cc][0];
            l += p;
            a0 += p * vA.x;  a1 += p * vA.y;
            a2 += p * vB.x;  a3 += p * vB.y;
            a4 += p * vC.x;  a5 += p * vC.y;
            a6 += p * vD.x;  a7 += p * vD.y;
        }
    }

    // ---- publish partials, merge across halves ----
    pm[half][tt] = mxh;
    pl[half][tt] = l;
    float4 own0 = {a0, a1, a2, a3};
    float4 own1 = {a4, a5, a6, a7};
    *(float4*)&pacc[half][tt][0] = own0;
    *(float4*)&pacc[half][tt][4] = own1;
    __syncthreads();

    const int oth = half ^ 1;
    const float m_o = pm[oth][tt];
    const float l_o = pl[oth][tt];
    const float4 po = (half == 0) ? *(const float4*)&pacc[oth][tt][0]
                                  : *(const float4*)&pacc[oth][tt][4];
    const float4 ow = (half == 0) ? own0 : own1;

    const float M = fmaxf(mxh, m_o);
    const float eo = __expf(mxh - M);
    const float eh = __expf(m_o - M);
    const float inv = 1.f / (l * eo + l_o * eh);

    const int a = sub >> 2, b = sub & 3;
    const int h = hs * 4 + a, w = wsc * 4 + b;
    unsigned short* op = o + (h * 128 + w) * 64 + head * 8 + half * 4;
    float rx = (ow.x * eo + po.x * eh) * inv;
    float ry = (ow.y * eo + po.y * eh) * inv;
    float rz = (ow.z * eo + po.z * eh) * inv;
    float rw = (ow.w * eo + po.w * eh) * inv;
    uint2 packed = {pack2bf(rx, ry), pack2bf(rz, rw)};
    *(uint2*)op = packed;
}

// ---------------- Kernel C: MFMA proj/fc1/fc2 + VALU LayerNorms ----------------
// oatt arrives pre-converted bf16 -> direct uint2 copy into LDS oh.
__global__ __launch_bounds__(256) void k_mlp(
    const float* __restrict__ x, const unsigned short* __restrict__ oatt,
    const unsigned short* __restrict__ pwh, const float* __restrict__ pb,
    const float* __restrict__ g1,
    const float* __restrict__ n2w, const float* __restrict__ n2b,
    const unsigned short* __restrict__ f1h, const float* __restrict__ f1b,
    const float* __restrict__ mnw, const float* __restrict__ mnb,
    const unsigned short* __restrict__ f2h, const float* __restrict__ f2b,
    const float* __restrict__ g2,
    float* __restrict__ out)
{
    __shared__ __align__(16) float xres[CC][ROW];
    __shared__ __align__(16) unsigned short oh[32][72];
    __shared__ __align__(16) unsigned short tbh[32][72];
    __shared__ __align__(16) float h1[HID][ROW];
    __shared__ __align__(16) unsigned short h1h[32][136];
    __shared__ __align__(16) float mu[32], rs[32];

    const int t = threadIdx.x;
    const int pix0 = blockIdx.x * 32;
    const int wv = t >> 6;
    const int l = t & 63;
    const int ln = l & 15;
    const int kg = l >> 4;

    {
        const int c = t >> 2, pxq = (t & 3) * 8;
        *(float4*)&xres[c][pxq]     = *(const float4*)(x + c * HW + pix0 + pxq);
        *(float4*)&xres[c][pxq + 4] = *(const float4*)(x + c * HW + pix0 + pxq + 4);
    }
    #pragma unroll
    for (int pass = 0; pass < 2; ++pass) {
        const int px = (t >> 4) + pass * 16, cg = (t & 15) * 4;
        uint2 ov = *(const uint2*)(oatt + (pix0 + px) * CC + cg);
        *(unsigned*)&oh[px][cg]     = ov.x;
        *(unsigned*)&oh[px][cg + 2] = ov.y;
    }
    __syncthreads();

    {
        f32x4v acc0 = {0.f, 0.f, 0.f, 0.f}, acc1 = {0.f, 0.f, 0.f, 0.f};
        const int m = wv * 16 + ln;
        #pragma unroll
        for (int kk = 0; kk < 64; kk += 32) {
            const int k0 = kk + kg * 8;
            bf16x8 av = *(const bf16x8*)(pwh + m * 64 + k0);
            bf16x8 b0 = *(const bf16x8*)&oh[ln][k0];
            bf16x8 b1 = *(const bf16x8*)&oh[16 + ln][k0];
            acc0 = __builtin_amdgcn_mfma_f32_16x16x32_bf16(av, b0, acc0, 0, 0, 0);
            acc1 = __builtin_amdgcn_mfma_f32_16x16x32_bf16(av, b1, acc1, 0, 0, 0);
        }
        const int r0 = wv * 16 + kg * 4;
        float4 pb4 = *(const float4*)(pb + r0);
        float4 g14 = *(const float4*)(g1 + r0);
        #pragma unroll
        for (int reg = 0; reg < 4; ++reg) {
            const int row = r0 + reg;
            xres[row][ln]      += (&g14.x)[reg] * (acc0[reg] + (&pb4.x)[reg]);
            xres[row][16 + ln] += (&g14.x)[reg] * (acc1[reg] + (&pb4.x)[reg]);
        }
    }
    __syncthreads();

    if (t < 128) {
        const int px = ((t >> 6) << 4) + (t & 15);
        const int part = (t & 63) >> 4;
        float s = 0.f, ss = 0.f;
        #pragma unroll
        for (int i = 0; i < 16; ++i) { float v = xres[part * 16 + i][px]; s += v; ss += v * v; }
        s += __shfl_xor(s, 16); ss += __shfl_xor(ss, 16);
        s += __shfl_xor(s, 32); ss += __shfl_xor(ss, 32);
        if (part == 0) {
            float m = s * (1.f / CC);
            mu[px] = m;
            rs[px] = rsqrtf(ss * (1.f / CC) - m * m + EPSV);
        }
    }
    __syncthreads();

    {
        const int c2 = (t & 31) * 2, px0 = (t >> 5) * 4;
        const float w0 = n2w[c2], b0 = n2b[c2];
        const float w1 = n2w[c2 + 1], b1 = n2b[c2 + 1];
        float4 va = *(float4*)&xres[c2][px0];
        float4 vb = *(float4*)&xres[c2 + 1][px0];
        float4 m4 = *(float4*)&mu[px0];
        float4 r4 = *(float4*)&rs[px0];
        #pragma unroll
        for (int i = 0; i < 4; ++i) {
            float f0 = ((&va.x)[i] - (&m4.x)[i]) * (&r4.x)[i] * w0 + b0;
            float f1 = ((&vb.x)[i] - (&m4.x)[i]) * (&r4.x)[i] * w1 + b1;
            *(unsigned*)&tbh[px0 + i][c2] = pack2bf(f0, f1);
        }
    }
    __syncthreads();

    {
        f32x4v a00 = {0.f,0.f,0.f,0.f}, a01 = {0.f,0.f,0.f,0.f};
        f32x4v a10 = {0.f,0.f,0.f,0.f}, a11 = {0.f,0.f,0.f,0.f};
        const int m0 = wv * 32 + ln;
        #pragma unroll
        for (int kk = 0; kk < 64; kk += 32) {
            const int k0 = kk + kg * 8;
            bf16x8 av0 = *(const bf16x8*)(f1h + m0 * 64 + k0);
            bf16x8 av1 = *(const bf16x8*)(f1h + (m0 + 16) * 64 + k0);
            bf16x8 b0 = *(const bf16x8*)&tbh[ln][k0];
            bf16x8 b1 = *(const bf16x8*)&tbh[16 + ln][k0];
            a00 = __builtin_amdgcn_mfma_f32_16x16x32_bf16(av0, b0, a00, 0, 0, 0);
            a01 = __builtin_amdgcn_mfma_f32_16x16x32_bf16(av0, b1, a01, 0, 0, 0);
            a10 = __builtin_amdgcn_mfma_f32_16x16x32_bf16(av1, b0, a10, 0, 0, 0);
            a11 = __builtin_amdgcn_mfma_f32_16x16x32_bf16(av1, b1, a11, 0, 0, 0);
        }
        const int r0 = wv * 32 + kg * 4;
        float4 fb0 = *(const float4*)(f1b + r0);
        float4 fb1 = *(const float4*)(f1b + r0 + 16);
        #pragma unroll
        for (int reg = 0; reg < 4; ++reg) {
            h1[r0 + reg][ln]           = a00[reg] + (&fb0.x)[reg];
            h1[r0 + reg][16 + ln]      = a01[reg] + (&fb0.x)[reg];
            h1[r0 + 16 + reg][ln]      = a10[reg] + (&fb1.x)[reg];
            h1[r0 + 16 + reg][16 + ln] = a11[reg] + (&fb1.x)[reg];
        }
    }
    __syncthreads();

    if (t < 128) {
        const int px = ((t >> 6) << 4) + (t & 15);
        const int part = (t & 63) >> 4;
        float s = 0.f, ss = 0.f;
        #pragma unroll
        for (int i = 0; i < 32; ++i) { float v = h1[part * 32 + i][px]; s += v; ss += v * v; }
        s += __shfl_xor(s, 16); ss += __shfl_xor(ss, 16);
        s += __shfl_xor(s, 32); ss += __shfl_xor(ss, 32);
        if (part == 0) {
            float m = s * (1.f / HID);
            mu[px] = m;
            rs[px] = rsqrtf(ss * (1.f / HID) - m * m + EPSV);
        }
    }
    __syncthreads();

    {
        const int c2 = (t & 63) * 2, pxm = (t >> 6) * 8;
        const float w0 = mnw[c2], b0 = mnb[c2];
        const float w1 = mnw[c2 + 1], b1 = mnb[c2 + 1];
        #pragma unroll
        for (int qq = 0; qq < 2; ++qq) {
            float4 va = *(float4*)&h1[c2][pxm + qq * 4];
            float4 vb = *(float4*)&h1[c2 + 1][pxm + qq * 4];
            float4 m4 = *(float4*)&mu[pxm + qq * 4];
            float4 r4 = *(float4*)&rs[pxm + qq * 4];
            #pragma unroll
            for (int i = 0; i < 4; ++i) {
                float h0 = ((&va.x)[i] - (&m4.x)[i]) * (&r4.x)[i] * w0 + b0;
                float h1v = ((&vb.x)[i] - (&m4.x)[i]) * (&r4.x)[i] * w1 + b1;
                h0 = h0 / (1.f + __expf(-h0));
                h1v = h1v / (1.f + __expf(-h1v));
                *(unsigned*)&h1h[pxm + qq * 4 + i][c2] = pack2bf(h0, h1v);
            }
        }
    }
    __syncthreads();

    {
        f32x4v acc0 = {0.f, 0.f, 0.f, 0.f}, acc1 = {0.f, 0.f, 0.f, 0.f};
        const int m = wv * 16 + ln;
        #pragma unroll
        for (int kk = 0; kk < 128; kk += 32) {
            const int k0 = kk + kg * 8;
            bf16x8 av = *(const bf16x8*)(f2h + m * 128 + k0);
            bf16x8 b0 = *(const bf16x8*)&h1h[ln][k0];
            bf16x8 b1 = *(const bf16x8*)&h1h[16 + ln][k0];
            acc0 = __builtin_amdgcn_mfma_f32_16x16x32_bf16(av, b0, acc0, 0, 0, 0);
            acc1 = __builtin_amdgcn_mfma_f32_16x16x32_bf16(av, b1, acc1, 0, 0, 0);
        }
        const int r0 = wv * 16 + kg * 4;
        float4 fb4 = *(const float4*)(f2b + r0);
        float4 g24 = *(const float4*)(g2 + r0);
        #pragma unroll
        for (int reg = 0; reg < 4; ++reg) {
            const int row = r0 + reg;
            out[row * HW + pix0 + ln]      = xres[row][ln]
                                           + (&g24.x)[reg] * (acc0[reg] + (&fb4.x)[reg]);
            out[row * HW + pix0 + 16 + ln] = xres[row][16 + ln]
                                           + (&g24.x)[reg] * (acc1[reg] + (&fb4.x)[reg]);
        }
    }
}

extern "C" void kernel_launch(void* const* d_in, const int* in_sizes, int n_in,
                              void* d_out, int out_size, void* d_ws, size_t ws_size,
                              hipStream_t stream) {
    (void)in_sizes; (void)n_in; (void)out_size; (void)ws_size;
    const float* x      = (const float*)d_in[0];
    const float* n1w    = (const float*)d_in[1];
    const float* n1b    = (const float*)d_in[2];
    const float* qkvw   = (const float*)d_in[3];
    const float* qkvb   = (const float*)d_in[4];
    const float* qnw    = (const float*)d_in[5];
    const float* qnb    = (const float*)d_in[6];
    const float* knw    = (const float*)d_in[7];
    const float* knb    = (const float*)d_in[8];
    const float* pw     = (const float*)d_in[9];
    const float* pb     = (const float*)d_in[10];
    const float* g1     = (const float*)d_in[11];
    const float* n2w    = (const float*)d_in[12];
    const float* n2b    = (const float*)d_in[13];
    const float* f1w    = (const float*)d_in[14];
    const float* f1b    = (const float*)d_in[15];
    const float* mnw    = (const float*)d_in[16];
    const float* mnb    = (const float*)d_in[17];
    const float* f2w    = (const float*)d_in[18];
    const float* f2b    = (const float*)d_in[19];
    const float* g2     = (const float*)d_in[20];
    float* out = (float*)d_out;

    float* ws = (float*)d_ws;
    const size_t CHW = (size_t)CC * HW;   // 1,048,576 floats
    float* qo   = ws;
    float* ko   = ws + CHW;
    float* vo   = ws + 2 * CHW;
    unsigned short* oatt = (unsigned short*)(ws + 3 * CHW);   // bf16, uses half the slot
    unsigned short* wsh = (unsigned short*)(ws + 4 * CHW);
    unsigned short* pwh = wsh;            // 4096
    unsigned short* f1h = wsh + 4096;     // 8192
    unsigned short* f2h = wsh + 12288;    // 8192

    k_ln_qkv<<<dim3(HW / 32), dim3(256), 0, stream>>>(
        x, n1w, n1b, qkvw, qkvb, qnw, qnb, knw, knb, qo, ko, vo);
    k_attn<<<dim3(4, 16, 8), dim3(512), 0, stream>>>(
        qo, ko, vo, oatt, pw, f1w, f2w, pwh, f1h, f2h);
    k_mlp<<<dim3(HW / 32), dim3(256), 0, stream>>>(
        x, oatt, pwh, pb, g1, n2w, n2b, f1h, f1b, mnw, mnb, f2h, f2b, g2, out);
}

// Round 12
// 128.346 us; speedup vs baseline: 1.0167x; 1.0107x over previous
//
#include <hip/hip_runtime.h>
#include <math.h>

#define HW 16384
#define CC 64
#define HID 128
#define EPSV 1e-5f
#define ROW 36     // padded LDS row for 32-pixel fp32 tiles
#define QROW2 133  // padded per-pixel row for q/k fp32 staging (128 + 5, odd)
#define HDSTR 131072    // per-head stride: 32*32*16*8 floats

typedef __attribute__((ext_vector_type(8))) short bf16x8;   // 8 bf16 = 4 VGPRs
typedef __attribute__((ext_vector_type(4))) float f32x4v;   // MFMA accumulator

__device__ __forceinline__ unsigned short f2bf(float f) {   // RNE fp32->bf16
    unsigned u = __float_as_uint(f);
    u += 0x7FFFu + ((u >> 16) & 1u);
    return (unsigned short)(u >> 16);
}
__device__ __forceinline__ unsigned pack2bf(float a, float b) {
    return (unsigned)f2bf(a) | ((unsigned)f2bf(b) << 16);
}

// q/k/v layout: [head][(hs*32+ws)*16 + sub][8], sub = (h&3)*4 + (w&3)

// ---------------- Kernel A: ln1 -> qkv via MFMA -> q/k LN -> ws ----------------
// LDS cut 67->50 KB (3 blocks/CU): xs/qk share one union buffer (xs dead after
// ln1-apply; qk written only after the next barrier), and v rows (no LN) are
// stored DIRECTLY from MFMA accumulators (lane holds 4 consecutive channels for
// its pixel; identical values to the old fp32-LDS round trip).
__global__ __launch_bounds__(256, 3) void k_ln_qkv(
    const float* __restrict__ x,
    const float* __restrict__ n1w, const float* __restrict__ n1b,
    const float* __restrict__ qkvw, const float* __restrict__ qkvb,
    const float* __restrict__ qnw, const float* __restrict__ qnb,
    const float* __restrict__ knw, const float* __restrict__ knb,
    float* __restrict__ qo, float* __restrict__ ko, float* __restrict__ vo)
{
    __shared__ __align__(16) char uni[32 * QROW2 * 4];       // union: xs[64][36] | qk[32][133]
    __shared__ __align__(16) unsigned short xh[32][72];      // ln1(x) bf16 [px][chan]
    __shared__ __align__(16) unsigned short wh[192][72];     // qkvw bf16 [out][k]
    __shared__ __align__(16) float mu1[32], rs1[32], muq[32], rsq[32], muk[32], rsk[32];

    float (*xs)[ROW]   = (float(*)[ROW])uni;     // valid until ln1-apply barrier
    float (*qk)[QROW2] = (float(*)[QROW2])uni;   // valid after MFMA epilogue

    const int t = threadIdx.x;
    const int pix0 = blockIdx.x * 32;
    const int wv = t >> 6;      // wave 0..3
    const int l = t & 63;
    const int ln = l & 15;      // frag col (px) / A-row within 16-stripe
    const int kg = l >> 4;      // frag k-group

    {
        const int c = t >> 2, pxq = (t & 3) * 8;
        *(float4*)&xs[c][pxq]     = *(const float4*)(x + c * HW + pix0 + pxq);
        *(float4*)&xs[c][pxq + 4] = *(const float4*)(x + c * HW + pix0 + pxq + 4);
    }
    #pragma unroll
    for (int i = 0; i < 12; ++i) {
        const int f = i * 256 + t;
        const int row = f >> 4;
        const int k4 = (f & 15) * 4;
        float4 wv4 = *(const float4*)(qkvw + row * 64 + k4);
        *(unsigned*)&wh[row][k4]     = pack2bf(wv4.x, wv4.y);
        *(unsigned*)&wh[row][k4 + 2] = pack2bf(wv4.z, wv4.w);
    }
    __syncthreads();

    if (t < 128) {
        const int px = ((t >> 6) << 4) + (t & 15);
        const int part = (t & 63) >> 4;
        float s = 0.f, ss = 0.f;
        #pragma unroll
        for (int i = 0; i < 16; ++i) { float v = xs[part * 16 + i][px]; s += v; ss += v * v; }
        s += __shfl_xor(s, 16); ss += __shfl_xor(ss, 16);
        s += __shfl_xor(s, 32); ss += __shfl_xor(ss, 32);
        if (part == 0) {
            float m = s * (1.f / CC);
            mu1[px] = m;
            rs1[px] = rsqrtf(ss * (1.f / CC) - m * m + EPSV);
        }
    }
    __syncthreads();

    {
        const int c2 = (t & 31) * 2, px0 = (t >> 5) * 4;
        const float w0 = n1w[c2], b0 = n1b[c2];
        const float w1 = n1w[c2 + 1], b1 = n1b[c2 + 1];
        float4 va = *(float4*)&xs[c2][px0];
        float4 vb = *(float4*)&xs[c2 + 1][px0];
        float4 m4 = *(float4*)&mu1[px0];
        float4 r4 = *(float4*)&rs1[px0];
        #pragma unroll
        for (int i = 0; i < 4; ++i) {
            float f0 = ((&va.x)[i] - (&m4.x)[i]) * (&r4.x)[i] * w0 + b0;
            float f1 = ((&vb.x)[i] - (&m4.x)[i]) * (&r4.x)[i] * w1 + b1;
            *(unsigned*)&xh[px0 + i][c2] = pack2bf(f0, f1);
        }
    }
    __syncthreads();    // xs dead from here; qk may now be written

    {
        f32x4v acc[3][2];
        #pragma unroll
        for (int mt = 0; mt < 3; ++mt) {
            acc[mt][0] = (f32x4v){0.f, 0.f, 0.f, 0.f};
            acc[mt][1] = (f32x4v){0.f, 0.f, 0.f, 0.f};
        }
        const int mbase = wv * 48;
        #pragma unroll
        for (int kk = 0; kk < 64; kk += 32) {
            const int k0 = kk + kg * 8;
            bf16x8 b0 = *(const bf16x8*)&xh[ln][k0];
            bf16x8 b1 = *(const bf16x8*)&xh[16 + ln][k0];
            #pragma unroll
            for (int mt = 0; mt < 3; ++mt) {
                bf16x8 av = *(const bf16x8*)&wh[mbase + mt * 16 + ln][k0];
                acc[mt][0] = __builtin_amdgcn_mfma_f32_16x16x32_bf16(av, b0, acc[mt][0], 0, 0, 0);
                acc[mt][1] = __builtin_amdgcn_mfma_f32_16x16x32_bf16(av, b1, acc[mt][1], 0, 0, 0);
            }
        }
        #pragma unroll
        for (int mt = 0; mt < 3; ++mt) {
            const int r0 = mbase + mt * 16 + kg * 4;
            float4 qb4 = *(const float4*)(qkvb + r0);
            if (mbase + mt * 16 < 128) {
                // q/k rows -> LDS staging for LN
                #pragma unroll
                for (int reg = 0; reg < 4; ++reg) {
                    qk[ln][r0 + reg]      = acc[mt][0][reg] + (&qb4.x)[reg];
                    qk[16 + ln][r0 + reg] = acc[mt][1][reg] + (&qb4.x)[reg];
                }
            } else {
                // v rows -> direct global store (no LN); 4 consecutive channels/lane
                const int c0 = r0 - 128;          // v channel base, c0&7 in {0,4}
                const int hd = c0 >> 3;
                const int d4 = c0 & 7;
                #pragma unroll
                for (int half = 0; half < 2; ++half) {
                    const int pixel = pix0 + half * 16 + ln;
                    const int h = pixel >> 7, w = pixel & 127;
                    const int pos = ((h >> 2) * 32 + (w >> 2)) * 16 + (h & 3) * 4 + (w & 3);
                    float4 vv = {acc[mt][half][0] + qb4.x, acc[mt][half][1] + qb4.y,
                                 acc[mt][half][2] + qb4.z, acc[mt][half][3] + qb4.w};
                    *(float4*)(vo + hd * HDSTR + pos * 8 + d4) = vv;
                }
            }
        }
    }
    __syncthreads();

    if (t < 128) {
        const int px = ((t >> 6) << 4) + (t & 15);
        const int part = (t & 63) >> 4;
        float s = 0.f, ss = 0.f;
        #pragma unroll
        for (int i = 0; i < 16; ++i) { float v = qk[px][part * 16 + i]; s += v; ss += v * v; }
        s += __shfl_xor(s, 16); ss += __shfl_xor(ss, 16);
        s += __shfl_xor(s, 32); ss += __shfl_xor(ss, 32);
        if (part == 0) {
            float m = s * (1.f / CC);
            muq[px] = m;
            rsq[px] = rsqrtf(ss * (1.f / CC) - m * m + EPSV);
        }
    } else {
        const int t2 = t - 128;
        const int px = ((t2 >> 6) << 4) + (t2 & 15);
        const int part = (t2 & 63) >> 4;
        float s = 0.f, ss = 0.f;
        #pragma unroll
        for (int i = 0; i < 16; ++i) { float v = qk[px][CC + part * 16 + i]; s += v; ss += v * v; }
        s += __shfl_xor(s, 16); ss += __shfl_xor(ss, 16);
        s += __shfl_xor(s, 32); ss += __shfl_xor(ss, 32);
        if (part == 0) {
            float m = s * (1.f / CC);
            muk[px] = m;
            rsk[px] = rsqrtf(ss * (1.f / CC) - m * m + EPSV);
        }
    }
    __syncthreads();

    // write q (LN), k (LN) to interleaved subgrid layout
    #pragma unroll
    for (int pass = 0; pass < 2; ++pass) {
        const int px = (t >> 4) + pass * 16;
        const int cg = t & 15;
        const int c = cg * 4;
        const int hd = cg >> 1;
        const int d4 = (cg & 1) * 4;
        const int pixel = pix0 + px;
        const int h = pixel >> 7, w = pixel & 127;
        const int pos = ((h >> 2) * 32 + (w >> 2)) * 16 + (h & 3) * 4 + (w & 3);
        const int gbase = hd * HDSTR + pos * 8 + d4;

        const float mq = muq[px], rq = rsq[px];
        float4 qv = *(float4*)&qk[px][c];
        float4 qw = *(const float4*)(qnw + c);
        float4 qb = *(const float4*)(qnb + c);
        qv.x = (qv.x - mq) * rq * qw.x + qb.x;
        qv.y = (qv.y - mq) * rq * qw.y + qb.y;
        qv.z = (qv.z - mq) * rq * qw.z + qb.z;
        qv.w = (qv.w - mq) * rq * qw.w + qb.w;
        *(float4*)(qo + gbase) = qv;

        const float mk = muk[px], rk = rsk[px];
        float4 kv = *(float4*)&qk[px][CC + c];
        float4 kw = *(const float4*)(knw + c);
        float4 kb = *(const float4*)(knb + c);
        kv.x = (kv.x - mk) * rk * kw.x + kb.x;
        kv.y = (kv.y - mk) * rk * kw.y + kb.y;
        kv.z = (kv.z - mk) * rk * kw.z + kb.z;
        kv.w = (kv.w - mk) * rk * kw.w + kb.w;
        *(float4*)(ko + gbase) = kv;
    }
}

// ---------------- Kernel B: NAT, 512 threads, neighbor-split 2-way + LDS merge ----------------
// oatt written as bf16 (identical rounding to C's previous read-side conversion).
__global__ __launch_bounds__(512, 4) void k_attn(
    const float* __restrict__ q, const float* __restrict__ k, const float* __restrict__ v,
    unsigned short* __restrict__ o,
    const float* __restrict__ pw, const float* __restrict__ f1w, const float* __restrict__ f2w,
    unsigned short* __restrict__ pwh, unsigned short* __restrict__ f1h,
    unsigned short* __restrict__ f2h)
{
    __shared__ __align__(16) float kt[4][15][33][2];
    __shared__ __align__(16) float vt[4][15][33][2];
    __shared__ __align__(16) float pm[2][256];
    __shared__ __align__(16) float pl[2][256];
    __shared__ __align__(16) float pacc[2][256][8];

    const int t = threadIdx.x;
    const int half = t >> 8;        // 0 or 1 (wave-uniform)
    const int tt = t & 255;
    const int band = blockIdx.x;
    const int sub  = blockIdx.y;
    const int head = blockIdx.z;
    const int hs0 = band * 8;

    // one-shot bf16 conversion of C's weights
    {
        const int gtid = ((blockIdx.z * 16 + blockIdx.y) * 4 + blockIdx.x) * 512 + t;
        if (gtid < 4096)        pwh[gtid] = f2bf(pw[gtid]);
        else if (gtid < 12288)  f1h[gtid - 4096] = f2bf(f1w[gtid - 4096]);
        else if (gtid < 20480)  f2h[gtid - 12288] = f2bf(f2w[gtid - 12288]);
    }

    const float* kb = k + head * HDSTR;
    const float* vb = v + head * HDSTR;

    for (int idx = t; idx < 960; idx += 512) {
        const int row = idx >> 6;
        const int rem = idx & 63;
        const int wsc = rem >> 1;
        const int dh = rem & 1;
        int gr = hs0 - 4 + row;
        gr = gr < 0 ? 0 : (gr > 31 ? 31 : gr);
        const int gaddr = ((gr * 32 + wsc) * 16 + sub) * 8 + dh * 4;
        const float4 kv4 = *(const float4*)(kb + gaddr);
        const float4 vv4 = *(const float4*)(vb + gaddr);
        const int dp = dh * 2;
        kt[dp][row][wsc][0] = kv4.x;     kt[dp][row][wsc][1] = kv4.y;
        kt[dp + 1][row][wsc][0] = kv4.z; kt[dp + 1][row][wsc][1] = kv4.w;
        vt[dp][row][wsc][0] = vv4.x;     vt[dp][row][wsc][1] = vv4.y;
        vt[dp + 1][row][wsc][0] = vv4.z; vt[dp + 1][row][wsc][1] = vv4.w;
    }

    const int r = tt >> 5;        // 0..7
    const int wsc = tt & 31;      // 0..31
    const int hs = hs0 + r;

    const float* qp = q + head * HDSTR + ((hs * 32 + wsc) * 16 + sub) * 8;
    const float4 q0 = *(const float4*)qp;
    const float4 q1 = *(const float4*)(qp + 4);
    const float scale = 0.35355339059327373f;   // 8^-0.5

    __syncthreads();

    // ---- pass 1: this half's 32 scores; 4-way parallel max ----
    float s[32];
    float mx0 = -1e30f, mx1 = -1e30f, mx2 = -1e30f, mx3 = -1e30f;
    #pragma unroll
    for (int ii = 0; ii < 4; ++ii) {
        const int i = half * 4 + ii;
        const int lr = r + i;
        const bool vh = (unsigned)(hs + i - 4) < 32u;
        #pragma unroll
        for (int j = 0; j < 8; ++j) {
            const int cs = wsc + j - 4;
            const bool valid = vh && ((unsigned)cs < 32u);
            const int cc = cs < 0 ? 0 : (cs > 31 ? 31 : cs);
            const float2 kA = *(const float2*)&kt[0][lr][cc][0];
            const float2 kB = *(const float2*)&kt[1][lr][cc][0];
            const float2 kC = *(const float2*)&kt[2][lr][cc][0];
            const float2 kD = *(const float2*)&kt[3][lr][cc][0];
            float sv = q0.x * kA.x + q0.y * kA.y + q0.z * kB.x + q0.w * kB.y
                     + q1.x * kC.x + q1.y * kC.y + q1.z * kD.x + q1.w * kD.y;
            sv *= scale;
            sv = valid ? sv : -INFINITY;
            s[ii * 8 + j] = sv;
            if ((j & 3) == 0)      mx0 = fmaxf(mx0, sv);
            else if ((j & 3) == 1) mx1 = fmaxf(mx1, sv);
            else if ((j & 3) == 2) mx2 = fmaxf(mx2, sv);
            else                   mx3 = fmaxf(mx3, sv);
        }
    }
    const float mxh = fmaxf(fmaxf(mx0, mx1), fmaxf(mx2, mx3));

    // ---- pass 2: exp + PV accumulate ----
    float l = 0.f;
    float a0 = 0.f, a1 = 0.f, a2 = 0.f, a3 = 0.f, a4 = 0.f, a5 = 0.f, a6 = 0.f, a7 = 0.f;
    #pragma unroll
    for (int ii = 0; ii < 4; ++ii) {
        const int i = half * 4 + ii;
        const int lr = r + i;
        #pragma unroll
        for (int j = 0; j < 8; ++j) {
            const int cs = wsc + j - 4;
            const int cc = cs < 0 ? 0 : (cs > 31 ? 31 : cs);
            const float p = __expf(s[ii * 8 + j] - mxh);
            const float2 vA = *(const float2*)&vt[0][lr][cc][0];
            const float2 vB = *(const float2*)&vt[1][lr][cc][0];
            const float2 vC = *(const float2*)&vt[2][lr][cc][0];
            const float2 vD = *(const float2*)&vt[3][lr][cc][0];
            l += p;
            a0 += p * vA.x;  a1 += p * vA.y;
            a2 += p * vB.x;  a3 += p * vB.y;
            a4 += p * vC.x;  a5 += p * vC.y;
            a6 += p * vD.x;  a7 += p * vD.y;
        }
    }

    // ---- publish partials, merge across halves ----
    pm[half][tt] = mxh;
    pl[half][tt] = l;
    float4 own0 = {a0, a1, a2, a3};
    float4 own1 = {a4, a5, a6, a7};
    *(float4*)&pacc[half][tt][0] = own0;
    *(float4*)&pacc[half][tt][4] = own1;
    __syncthreads();

    const int oth = half ^ 1;
    const float m_o = pm[oth][tt];
    const float l_o = pl[oth][tt];
    const float4 po = (half == 0) ? *(const float4*)&pacc[oth][tt][0]
                                  : *(const float4*)&pacc[oth][tt][4];
    const float4 ow = (half == 0) ? own0 : own1;

    const float M = fmaxf(mxh, m_o);
    const float eo = __expf(mxh - M);
    const float eh = __expf(m_o - M);
    const float inv = 1.f / (l * eo + l_o * eh);

    const int a = sub >> 2, b = sub & 3;
    const int h = hs * 4 + a, w = wsc * 4 + b;
    unsigned short* op = o + (h * 128 + w) * 64 + head * 8 + half * 4;
    float rx = (ow.x * eo + po.x * eh) * inv;
    float ry = (ow.y * eo + po.y * eh) * inv;
    float rz = (ow.z * eo + po.z * eh) * inv;
    float rw = (ow.w * eo + po.w * eh) * inv;
    uint2 packed = {pack2bf(rx, ry), pack2bf(rz, rw)};
    *(uint2*)op = packed;
}

// ---------------- Kernel C: MFMA proj/fc1/fc2 + VALU LayerNorms ----------------
// oatt arrives pre-converted bf16 -> direct uint2 copy into LDS oh.
__global__ __launch_bounds__(256) void k_mlp(
    const float* __restrict__ x, const unsigned short* __restrict__ oatt,
    const unsigned short* __restrict__ pwh, const float* __restrict__ pb,
    const float* __restrict__ g1,
    const float* __restrict__ n2w, const float* __restrict__ n2b,
    const unsigned short* __restrict__ f1h, const float* __restrict__ f1b,
    const float* __restrict__ mnw, const float* __restrict__ mnb,
    const unsigned short* __restrict__ f2h, const float* __restrict__ f2b,
    const float* __restrict__ g2,
    float* __restrict__ out)
{
    __shared__ __align__(16) float xres[CC][ROW];
    __shared__ __align__(16) unsigned short oh[32][72];
    __shared__ __align__(16) unsigned short tbh[32][72];
    __shared__ __align__(16) float h1[HID][ROW];
    __shared__ __align__(16) unsigned short h1h[32][136];
    __shared__ __align__(16) float mu[32], rs[32];

    const int t = threadIdx.x;
    const int pix0 = blockIdx.x * 32;
    const int wv = t >> 6;
    const int l = t & 63;
    const int ln = l & 15;
    const int kg = l >> 4;

    {
        const int c = t >> 2, pxq = (t & 3) * 8;
        *(float4*)&xres[c][pxq]     = *(const float4*)(x + c * HW + pix0 + pxq);
        *(float4*)&xres[c][pxq + 4] = *(const float4*)(x + c * HW + pix0 + pxq + 4);
    }
    #pragma unroll
    for (int pass = 0; pass < 2; ++pass) {
        const int px = (t >> 4) + pass * 16, cg = (t & 15) * 4;
        uint2 ov = *(const uint2*)(oatt + (pix0 + px) * CC + cg);
        *(unsigned*)&oh[px][cg]     = ov.x;
        *(unsigned*)&oh[px][cg + 2] = ov.y;
    }
    __syncthreads();

    {
        f32x4v acc0 = {0.f, 0.f, 0.f, 0.f}, acc1 = {0.f, 0.f, 0.f, 0.f};
        const int m = wv * 16 + ln;
        #pragma unroll
        for (int kk = 0; kk < 64; kk += 32) {
            const int k0 = kk + kg * 8;
            bf16x8 av = *(const bf16x8*)(pwh + m * 64 + k0);
            bf16x8 b0 = *(const bf16x8*)&oh[ln][k0];
            bf16x8 b1 = *(const bf16x8*)&oh[16 + ln][k0];
            acc0 = __builtin_amdgcn_mfma_f32_16x16x32_bf16(av, b0, acc0, 0, 0, 0);
            acc1 = __builtin_amdgcn_mfma_f32_16x16x32_bf16(av, b1, acc1, 0, 0, 0);
        }
        const int r0 = wv * 16 + kg * 4;
        float4 pb4 = *(const float4*)(pb + r0);
        float4 g14 = *(const float4*)(g1 + r0);
        #pragma unroll
        for (int reg = 0; reg < 4; ++reg) {
            const int row = r0 + reg;
            xres[row][ln]      += (&g14.x)[reg] * (acc0[reg] + (&pb4.x)[reg]);
            xres[row][16 + ln] += (&g14.x)[reg] * (acc1[reg] + (&pb4.x)[reg]);
        }
    }
    __syncthreads();

    if (t < 128) {
        const int px = ((t >> 6) << 4) + (t & 15);
        const int part = (t & 63) >> 4;
        float s = 0.f, ss = 0.f;
        #pragma unroll
        for (int i = 0; i < 16; ++i) { float v = xres[part * 16 + i][px]; s += v; ss += v * v; }
        s += __shfl_xor(s, 16); ss += __shfl_xor(ss, 16);
        s += __shfl_xor(s, 32); ss += __shfl_xor(ss, 32);
        if (part == 0) {
            float m = s * (1.f / CC);
            mu[px] = m;
            rs[px] = rsqrtf(ss * (1.f / CC) - m * m + EPSV);
        }
    }
    __syncthreads();

    {
        const int c2 = (t & 31) * 2, px0 = (t >> 5) * 4;
        const float w0 = n2w[c2], b0 = n2b[c2];
        const float w1 = n2w[c2 + 1], b1 = n2b[c2 + 1];
        float4 va = *(float4*)&xres[c2][px0];
        float4 vb = *(float4*)&xres[c2 + 1][px0];
        float4 m4 = *(float4*)&mu[px0];
        float4 r4 = *(float4*)&rs[px0];
        #pragma unroll
        for (int i = 0; i < 4; ++i) {
            float f0 = ((&va.x)[i] - (&m4.x)[i]) * (&r4.x)[i] * w0 + b0;
            float f1 = ((&vb.x)[i] - (&m4.x)[i]) * (&r4.x)[i] * w1 + b1;
            *(unsigned*)&tbh[px0 + i][c2] = pack2bf(f0, f1);
        }
    }
    __syncthreads();

    {
        f32x4v a00 = {0.f,0.f,0.f,0.f}, a01 = {0.f,0.f,0.f,0.f};
        f32x4v a10 = {0.f,0.f,0.f,0.f}, a11 = {0.f,0.f,0.f,0.f};
        const int m0 = wv * 32 + ln;
        #pragma unroll
        for (int kk = 0; kk < 64; kk += 32) {
            const int k0 = kk + kg * 8;
            bf16x8 av0 = *(const bf16x8*)(f1h + m0 * 64 + k0);
            bf16x8 av1 = *(const bf16x8*)(f1h + (m0 + 16) * 64 + k0);
            bf16x8 b0 = *(const bf16x8*)&tbh[ln][k0];
            bf16x8 b1 = *(const bf16x8*)&tbh[16 + ln][k0];
            a00 = __builtin_amdgcn_mfma_f32_16x16x32_bf16(av0, b0, a00, 0, 0, 0);
            a01 = __builtin_amdgcn_mfma_f32_16x16x32_bf16(av0, b1, a01, 0, 0, 0);
            a10 = __builtin_amdgcn_mfma_f32_16x16x32_bf16(av1, b0, a10, 0, 0, 0);
            a11 = __builtin_amdgcn_mfma_f32_16x16x32_bf16(av1, b1, a11, 0, 0, 0);
        }
        const int r0 = wv * 32 + kg * 4;
        float4 fb0 = *(const float4*)(f1b + r0);
        float4 fb1 = *(const float4*)(f1b + r0 + 16);
        #pragma unroll
        for (int reg = 0; reg < 4; ++reg) {
            h1[r0 + reg][ln]           = a00[reg] + (&fb0.x)[reg];
            h1[r0 + reg][16 + ln]      = a01[reg] + (&fb0.x)[reg];
            h1[r0 + 16 + reg][ln]      = a10[reg] + (&fb1.x)[reg];
            h1[r0 + 16 + reg][16 + ln] = a11[reg] + (&fb1.x)[reg];
        }
    }
    __syncthreads();

    if (t < 128) {
        const int px = ((t >> 6) << 4) + (t & 15);
        const int part = (t & 63) >> 4;
        float s = 0.f, ss = 0.f;
        #pragma unroll
        for (int i = 0; i < 32; ++i) { float v = h1[part * 32 + i][px]; s += v; ss += v * v; }
        s += __shfl_xor(s, 16); ss += __shfl_xor(ss, 16);
        s += __shfl_xor(s, 32); ss += __shfl_xor(ss, 32);
        if (part == 0) {
            float m = s * (1.f / HID);
            mu[px] = m;
            rs[px] = rsqrtf(ss * (1.f / HID) - m * m + EPSV);
        }
    }
    __syncthreads();

    {
        const int c2 = (t & 63) * 2, pxm = (t >> 6) * 8;
        const float w0 = mnw[c2], b0 = mnb[c2];
        const float w1 = mnw[c2 + 1], b1 = mnb[c2 + 1];
        #pragma unroll
        for (int qq = 0; qq < 2; ++qq) {
            float4 va = *(float4*)&h1[c2][pxm + qq * 4];
            float4 vb = *(float4*)&h1[c2 + 1][pxm + qq * 4];
            float4 m4 = *(float4*)&mu[pxm + qq * 4];
            float4 r4 = *(float4*)&rs[pxm + qq * 4];
            #pragma unroll
            for (int i = 0; i < 4; ++i) {
                float h0 = ((&va.x)[i] - (&m4.x)[i]) * (&r4.x)[i] * w0 + b0;
                float h1v = ((&vb.x)[i] - (&m4.x)[i]) * (&r4.x)[i] * w1 + b1;
                h0 = h0 / (1.f + __expf(-h0));
                h1v = h1v / (1.f + __expf(-h1v));
                *(unsigned*)&h1h[pxm + qq * 4 + i][c2] = pack2bf(h0, h1v);
            }
        }
    }
    __syncthreads();

    {
        f32x4v acc0 = {0.f, 0.f, 0.f, 0.f}, acc1 = {0.f, 0.f, 0.f, 0.f};
        const int m = wv * 16 + ln;
        #pragma unroll
        for (int kk = 0; kk < 128; kk += 32) {
            const int k0 = kk + kg * 8;
            bf16x8 av = *(const bf16x8*)(f2h + m * 128 + k0);
            bf16x8 b0 = *(const bf16x8*)&h1h[ln][k0];
            bf16x8 b1 = *(const bf16x8*)&h1h[16 + ln][k0];
            acc0 = __builtin_amdgcn_mfma_f32_16x16x32_bf16(av, b0, acc0, 0, 0, 0);
            acc1 = __builtin_amdgcn_mfma_f32_16x16x32_bf16(av, b1, acc1, 0, 0, 0);
        }
        const int r0 = wv * 16 + kg * 4;
        float4 fb4 = *(const float4*)(f2b + r0);
        float4 g24 = *(const float4*)(g2 + r0);
        #pragma unroll
        for (int reg = 0; reg < 4; ++reg) {
            const int row = r0 + reg;
            out[row * HW + pix0 + ln]      = xres[row][ln]
                                           + (&g24.x)[reg] * (acc0[reg] + (&fb4.x)[reg]);
            out[row * HW + pix0 + 16 + ln] = xres[row][16 + ln]
                                           + (&g24.x)[reg] * (acc1[reg] + (&fb4.x)[reg]);
        }
    }
}

extern "C" void kernel_launch(void* const* d_in, const int* in_sizes, int n_in,
                              void* d_out, int out_size, void* d_ws, size_t ws_size,
                              hipStream_t stream) {
    (void)in_sizes; (void)n_in; (void)out_size; (void)ws_size;
    const float* x      = (const float*)d_in[0];
    const float* n1w    = (const float*)d_in[1];
    const float* n1b    = (const float*)d_in[2];
    const float* qkvw   = (const float*)d_in[3];
    const float* qkvb   = (const float*)d_in[4];
    const float* qnw    = (const float*)d_in[5];
    const float* qnb    = (const float*)d_in[6];
    const float* knw    = (const float*)d_in[7];
    const float* knb    = (const float*)d_in[8];
    const float* pw     = (const float*)d_in[9];
    const float* pb     = (const float*)d_in[10];
    const float* g1     = (const float*)d_in[11];
    const float* n2w    = (const float*)d_in[12];
    const float* n2b    = (const float*)d_in[13];
    const float* f1w    = (const float*)d_in[14];
    const float* f1b    = (const float*)d_in[15];
    const float* mnw    = (const float*)d_in[16];
    const float* mnb    = (const float*)d_in[17];
    const float* f2w    = (const float*)d_in[18];
    const float* f2b    = (const float*)d_in[19];
    const float* g2     = (const float*)d_in[20];
    float* out = (float*)d_out;

    float* ws = (float*)d_ws;
    const size_t CHW = (size_t)CC * HW;   // 1,048,576 floats
    float* qo   = ws;
    float* ko   = ws + CHW;
    float* vo   = ws + 2 * CHW;
    unsigned short* oatt = (unsigned short*)(ws + 3 * CHW);   // bf16, uses half the slot
    unsigned short* wsh = (unsigned short*)(ws + 4 * CHW);
    unsigned short* pwh = wsh;            // 4096
    unsigned short* f1h = wsh + 4096;     // 8192
    unsigned short* f2h = wsh + 12288;    // 8192

    k_ln_qkv<<<dim3(HW / 32), dim3(256), 0, stream>>>(
        x, n1w, n1b, qkvw, qkvb, qnw, qnb, knw, knb, qo, ko, vo);
    k_attn<<<dim3(4, 16, 8), dim3(512), 0, stream>>>(
        qo, ko, vo, oatt, pw, f1w, f2w, pwh, f1h, f2h);
    k_mlp<<<dim3(HW / 32), dim3(256), 0, stream>>>(
        x, oatt, pwh, pb, g1, n2w, n2b, f1h, f1b, mnw, mnb, f2h, f2b, g2, out);
}

// Round 13
// 126.639 us; speedup vs baseline: 1.0304x; 1.0135x over previous
//
#include <hip/hip_runtime.h>
#include <math.h>

#define HW 16384
#define CC 64
#define HID 128
#define EPSV 1e-5f
#define ROW 36     // padded LDS row for 32-pixel fp32 tiles
#define QROW2 133  // padded per-pixel row for q/k fp32 staging (128 + 5, odd)
#define HDSTR 131072    // per-head stride: 32*32*16*8 elements (now bf16)

typedef __attribute__((ext_vector_type(8))) short bf16x8;   // 8 bf16 = 4 VGPRs
typedef __attribute__((ext_vector_type(4))) float f32x4v;   // MFMA accumulator

__device__ __forceinline__ unsigned short f2bf(float f) {   // RNE fp32->bf16
    unsigned u = __float_as_uint(f);
    u += 0x7FFFu + ((u >> 16) & 1u);
    return (unsigned short)(u >> 16);
}
__device__ __forceinline__ unsigned pack2bf(float a, float b) {
    return (unsigned)f2bf(a) | ((unsigned)f2bf(b) << 16);
}
__device__ __forceinline__ float bflo(unsigned u) { return __uint_as_float(u << 16); }
__device__ __forceinline__ float bfhi(unsigned u) { return __uint_as_float(u & 0xFFFF0000u); }

// q/k/v layout: [head][(hs*32+ws)*16 + sub][8] bf16, sub = (h&3)*4 + (w&3)

// ---------------- Kernel A: ln1 -> qkv via MFMA -> q/k LN -> ws (bf16 out) ----------------
__global__ __launch_bounds__(256, 3) void k_ln_qkv(
    const float* __restrict__ x,
    const float* __restrict__ n1w, const float* __restrict__ n1b,
    const float* __restrict__ qkvw, const float* __restrict__ qkvb,
    const float* __restrict__ qnw, const float* __restrict__ qnb,
    const float* __restrict__ knw, const float* __restrict__ knb,
    unsigned short* __restrict__ qo, unsigned short* __restrict__ ko,
    unsigned short* __restrict__ vo)
{
    __shared__ __align__(16) char uni[32 * QROW2 * 4];       // union: xs[64][36] | qk[32][133]
    __shared__ __align__(16) unsigned short xh[32][72];      // ln1(x) bf16 [px][chan]
    __shared__ __align__(16) unsigned short wh[192][72];     // qkvw bf16 [out][k]
    __shared__ __align__(16) float mu1[32], rs1[32], muq[32], rsq[32], muk[32], rsk[32];

    float (*xs)[ROW]   = (float(*)[ROW])uni;     // valid until ln1-apply barrier
    float (*qk)[QROW2] = (float(*)[QROW2])uni;   // valid after MFMA epilogue

    const int t = threadIdx.x;
    const int pix0 = blockIdx.x * 32;
    const int wv = t >> 6;      // wave 0..3
    const int l = t & 63;
    const int ln = l & 15;      // frag col (px) / A-row within 16-stripe
    const int kg = l >> 4;      // frag k-group

    {
        const int c = t >> 2, pxq = (t & 3) * 8;
        *(float4*)&xs[c][pxq]     = *(const float4*)(x + c * HW + pix0 + pxq);
        *(float4*)&xs[c][pxq + 4] = *(const float4*)(x + c * HW + pix0 + pxq + 4);
    }
    #pragma unroll
    for (int i = 0; i < 12; ++i) {
        const int f = i * 256 + t;
        const int row = f >> 4;
        const int k4 = (f & 15) * 4;
        float4 wv4 = *(const float4*)(qkvw + row * 64 + k4);
        *(unsigned*)&wh[row][k4]     = pack2bf(wv4.x, wv4.y);
        *(unsigned*)&wh[row][k4 + 2] = pack2bf(wv4.z, wv4.w);
    }
    __syncthreads();

    if (t < 128) {
        const int px = ((t >> 6) << 4) + (t & 15);
        const int part = (t & 63) >> 4;
        float s = 0.f, ss = 0.f;
        #pragma unroll
        for (int i = 0; i < 16; ++i) { float v = xs[part * 16 + i][px]; s += v; ss += v * v; }
        s += __shfl_xor(s, 16); ss += __shfl_xor(ss, 16);
        s += __shfl_xor(s, 32); ss += __shfl_xor(ss, 32);
        if (part == 0) {
            float m = s * (1.f / CC);
            mu1[px] = m;
            rs1[px] = rsqrtf(ss * (1.f / CC) - m * m + EPSV);
        }
    }
    __syncthreads();

    {
        const int c2 = (t & 31) * 2, px0 = (t >> 5) * 4;
        const float w0 = n1w[c2], b0 = n1b[c2];
        const float w1 = n1w[c2 + 1], b1 = n1b[c2 + 1];
        float4 va = *(float4*)&xs[c2][px0];
        float4 vb = *(float4*)&xs[c2 + 1][px0];
        float4 m4 = *(float4*)&mu1[px0];
        float4 r4 = *(float4*)&rs1[px0];
        #pragma unroll
        for (int i = 0; i < 4; ++i) {
            float f0 = ((&va.x)[i] - (&m4.x)[i]) * (&r4.x)[i] * w0 + b0;
            float f1 = ((&vb.x)[i] - (&m4.x)[i]) * (&r4.x)[i] * w1 + b1;
            *(unsigned*)&xh[px0 + i][c2] = pack2bf(f0, f1);
        }
    }
    __syncthreads();    // xs dead from here; qk may now be written

    {
        f32x4v acc[3][2];
        #pragma unroll
        for (int mt = 0; mt < 3; ++mt) {
            acc[mt][0] = (f32x4v){0.f, 0.f, 0.f, 0.f};
            acc[mt][1] = (f32x4v){0.f, 0.f, 0.f, 0.f};
        }
        const int mbase = wv * 48;
        #pragma unroll
        for (int kk = 0; kk < 64; kk += 32) {
            const int k0 = kk + kg * 8;
            bf16x8 b0 = *(const bf16x8*)&xh[ln][k0];
            bf16x8 b1 = *(const bf16x8*)&xh[16 + ln][k0];
            #pragma unroll
            for (int mt = 0; mt < 3; ++mt) {
                bf16x8 av = *(const bf16x8*)&wh[mbase + mt * 16 + ln][k0];
                acc[mt][0] = __builtin_amdgcn_mfma_f32_16x16x32_bf16(av, b0, acc[mt][0], 0, 0, 0);
                acc[mt][1] = __builtin_amdgcn_mfma_f32_16x16x32_bf16(av, b1, acc[mt][1], 0, 0, 0);
            }
        }
        #pragma unroll
        for (int mt = 0; mt < 3; ++mt) {
            const int r0 = mbase + mt * 16 + kg * 4;
            float4 qb4 = *(const float4*)(qkvb + r0);
            if (mbase + mt * 16 < 128) {
                // q/k rows -> LDS staging for LN
                #pragma unroll
                for (int reg = 0; reg < 4; ++reg) {
                    qk[ln][r0 + reg]      = acc[mt][0][reg] + (&qb4.x)[reg];
                    qk[16 + ln][r0 + reg] = acc[mt][1][reg] + (&qb4.x)[reg];
                }
            } else {
                // v rows -> direct bf16 global store (no LN); 4 consecutive channels/lane
                const int c0 = r0 - 128;          // v channel base, c0&7 in {0,4}
                const int hd = c0 >> 3;
                const int d4 = c0 & 7;
                #pragma unroll
                for (int half = 0; half < 2; ++half) {
                    const int pixel = pix0 + half * 16 + ln;
                    const int h = pixel >> 7, w = pixel & 127;
                    const int pos = ((h >> 2) * 32 + (w >> 2)) * 16 + (h & 3) * 4 + (w & 3);
                    uint2 vv = {pack2bf(acc[mt][half][0] + qb4.x, acc[mt][half][1] + qb4.y),
                                pack2bf(acc[mt][half][2] + qb4.z, acc[mt][half][3] + qb4.w)};
                    *(uint2*)(vo + hd * HDSTR + pos * 8 + d4) = vv;
                }
            }
        }
    }
    __syncthreads();

    if (t < 128) {
        const int px = ((t >> 6) << 4) + (t & 15);
        const int part = (t & 63) >> 4;
        float s = 0.f, ss = 0.f;
        #pragma unroll
        for (int i = 0; i < 16; ++i) { float v = qk[px][part * 16 + i]; s += v; ss += v * v; }
        s += __shfl_xor(s, 16); ss += __shfl_xor(ss, 16);
        s += __shfl_xor(s, 32); ss += __shfl_xor(ss, 32);
        if (part == 0) {
            float m = s * (1.f / CC);
            muq[px] = m;
            rsq[px] = rsqrtf(ss * (1.f / CC) - m * m + EPSV);
        }
    } else {
        const int t2 = t - 128;
        const int px = ((t2 >> 6) << 4) + (t2 & 15);
        const int part = (t2 & 63) >> 4;
        float s = 0.f, ss = 0.f;
        #pragma unroll
        for (int i = 0; i < 16; ++i) { float v = qk[px][CC + part * 16 + i]; s += v; ss += v * v; }
        s += __shfl_xor(s, 16); ss += __shfl_xor(ss, 16);
        s += __shfl_xor(s, 32); ss += __shfl_xor(ss, 32);
        if (part == 0) {
            float m = s * (1.f / CC);
            muk[px] = m;
            rsk[px] = rsqrtf(ss * (1.f / CC) - m * m + EPSV);
        }
    }
    __syncthreads();

    // write q (LN), k (LN) as bf16 to interleaved subgrid layout
    #pragma unroll
    for (int pass = 0; pass < 2; ++pass) {
        const int px = (t >> 4) + pass * 16;
        const int cg = t & 15;
        const int c = cg * 4;
        const int hd = cg >> 1;
        const int d4 = (cg & 1) * 4;
        const int pixel = pix0 + px;
        const int h = pixel >> 7, w = pixel & 127;
        const int pos = ((h >> 2) * 32 + (w >> 2)) * 16 + (h & 3) * 4 + (w & 3);
        const int gbase = hd * HDSTR + pos * 8 + d4;

        const float mq = muq[px], rq = rsq[px];
        float4 qv = *(float4*)&qk[px][c];
        float4 qw = *(const float4*)(qnw + c);
        float4 qb = *(const float4*)(qnb + c);
        qv.x = (qv.x - mq) * rq * qw.x + qb.x;
        qv.y = (qv.y - mq) * rq * qw.y + qb.y;
        qv.z = (qv.z - mq) * rq * qw.z + qb.z;
        qv.w = (qv.w - mq) * rq * qw.w + qb.w;
        uint2 qpk = {pack2bf(qv.x, qv.y), pack2bf(qv.z, qv.w)};
        *(uint2*)(qo + gbase) = qpk;

        const float mk = muk[px], rk = rsk[px];
        float4 kv = *(float4*)&qk[px][CC + c];
        float4 kw = *(const float4*)(knw + c);
        float4 kb = *(const float4*)(knb + c);
        kv.x = (kv.x - mk) * rk * kw.x + kb.x;
        kv.y = (kv.y - mk) * rk * kw.y + kb.y;
        kv.z = (kv.z - mk) * rk * kw.z + kb.z;
        kv.w = (kv.w - mk) * rk * kw.w + kb.w;
        uint2 kpk = {pack2bf(kv.x, kv.y), pack2bf(kv.z, kv.w)};
        *(uint2*)(ko + gbase) = kpk;
    }
}

// ---------------- Kernel B: NAT, 512 threads, neighbor-split 2-way + LDS merge ----------------
// q/k/v read as bf16 from global; k/v unpacked to fp32 during LDS staging so the
// inner loop is byte-identical to the verified r9 version.
__global__ __launch_bounds__(512, 4) void k_attn(
    const unsigned short* __restrict__ q, const unsigned short* __restrict__ k,
    const unsigned short* __restrict__ v,
    unsigned short* __restrict__ o,
    const float* __restrict__ pw, const float* __restrict__ f1w, const float* __restrict__ f2w,
    unsigned short* __restrict__ pwh, unsigned short* __restrict__ f1h,
    unsigned short* __restrict__ f2h)
{
    __shared__ __align__(16) float kt[4][15][33][2];
    __shared__ __align__(16) float vt[4][15][33][2];
    __shared__ __align__(16) float pm[2][256];
    __shared__ __align__(16) float pl[2][256];
    __shared__ __align__(16) float pacc[2][256][8];

    const int t = threadIdx.x;
    const int half = t >> 8;        // 0 or 1 (wave-uniform)
    const int tt = t & 255;
    const int band = blockIdx.x;
    const int sub  = blockIdx.y;
    const int head = blockIdx.z;
    const int hs0 = band * 8;

    // one-shot bf16 conversion of C's weights
    {
        const int gtid = ((blockIdx.z * 16 + blockIdx.y) * 4 + blockIdx.x) * 512 + t;
        if (gtid < 4096)        pwh[gtid] = f2bf(pw[gtid]);
        else if (gtid < 12288)  f1h[gtid - 4096] = f2bf(f1w[gtid - 4096]);
        else if (gtid < 20480)  f2h[gtid - 12288] = f2bf(f2w[gtid - 12288]);
    }

    const unsigned short* kb = k + head * HDSTR;
    const unsigned short* vb = v + head * HDSTR;

    // stage k/v subgrid rows hs0-4 .. hs0+10 (clamped): 480 pixels, uint4 each
    for (int idx = t; idx < 480; idx += 512) {
        const int row = idx >> 5;       // 0..14
        const int wsc = idx & 31;
        int gr = hs0 - 4 + row;
        gr = gr < 0 ? 0 : (gr > 31 ? 31 : gr);
        const int gaddr = ((gr * 32 + wsc) * 16 + sub) * 8;
        const uint4 kv4 = *(const uint4*)(kb + gaddr);
        const uint4 vv4 = *(const uint4*)(vb + gaddr);
        kt[0][row][wsc][0] = bflo(kv4.x); kt[0][row][wsc][1] = bfhi(kv4.x);
        kt[1][row][wsc][0] = bflo(kv4.y); kt[1][row][wsc][1] = bfhi(kv4.y);
        kt[2][row][wsc][0] = bflo(kv4.z); kt[2][row][wsc][1] = bfhi(kv4.z);
        kt[3][row][wsc][0] = bflo(kv4.w); kt[3][row][wsc][1] = bfhi(kv4.w);
        vt[0][row][wsc][0] = bflo(vv4.x); vt[0][row][wsc][1] = bfhi(vv4.x);
        vt[1][row][wsc][0] = bflo(vv4.y); vt[1][row][wsc][1] = bfhi(vv4.y);
        vt[2][row][wsc][0] = bflo(vv4.z); vt[2][row][wsc][1] = bfhi(vv4.z);
        vt[3][row][wsc][0] = bflo(vv4.w); vt[3][row][wsc][1] = bfhi(vv4.w);
    }

    const int r = tt >> 5;        // 0..7
    const int wsc = tt & 31;      // 0..31
    const int hs = hs0 + r;

    const unsigned short* qp = q + head * HDSTR + ((hs * 32 + wsc) * 16 + sub) * 8;
    const uint4 qv4 = *(const uint4*)qp;
    const float4 q0 = {bflo(qv4.x), bfhi(qv4.x), bflo(qv4.y), bfhi(qv4.y)};
    const float4 q1 = {bflo(qv4.z), bfhi(qv4.z), bflo(qv4.w), bfhi(qv4.w)};
    const float scale = 0.35355339059327373f;   // 8^-0.5

    __syncthreads();

    // ---- pass 1: this half's 32 scores; 4-way parallel max ----
    float s[32];
    float mx0 = -1e30f, mx1 = -1e30f, mx2 = -1e30f, mx3 = -1e30f;
    #pragma unroll
    for (int ii = 0; ii < 4; ++ii) {
        const int i = half * 4 + ii;
        const int lr = r + i;
        const bool vh = (unsigned)(hs + i - 4) < 32u;
        #pragma unroll
        for (int j = 0; j < 8; ++j) {
            const int cs = wsc + j - 4;
            const bool valid = vh && ((unsigned)cs < 32u);
            const int cc = cs < 0 ? 0 : (cs > 31 ? 31 : cs);
            const float2 kA = *(const float2*)&kt[0][lr][cc][0];
            const float2 kB = *(const float2*)&kt[1][lr][cc][0];
            const float2 kC = *(const float2*)&kt[2][lr][cc][0];
            const float2 kD = *(const float2*)&kt[3][lr][cc][0];
            float sv = q0.x * kA.x + q0.y * kA.y + q0.z * kB.x + q0.w * kB.y
                     + q1.x * kC.x + q1.y * kC.y + q1.z * kD.x + q1.w * kD.y;
            sv *= scale;
            sv = valid ? sv : -INFINITY;
            s[ii * 8 + j] = sv;
            if ((j & 3) == 0)      mx0 = fmaxf(mx0, sv);
            else if ((j & 3) == 1) mx1 = fmaxf(mx1, sv);
            else if ((j & 3) == 2) mx2 = fmaxf(mx2, sv);
            else                   mx3 = fmaxf(mx3, sv);
        }
    }
    const float mxh = fmaxf(fmaxf(mx0, mx1), fmaxf(mx2, mx3));

    // ---- pass 2: exp + PV accumulate ----
    float l = 0.f;
    float a0 = 0.f, a1 = 0.f, a2 = 0.f, a3 = 0.f, a4 = 0.f, a5 = 0.f, a6 = 0.f, a7 = 0.f;
    #pragma unroll
    for (int ii = 0; ii < 4; ++ii) {
        const int i = half * 4 + ii;
        const int lr = r + i;
        #pragma unroll
        for (int j = 0; j < 8; ++j) {
            const int cs = wsc + j - 4;
            const int cc = cs < 0 ? 0 : (cs > 31 ? 31 : cs);
            const float p = __expf(s[ii * 8 + j] - mxh);
            const float2 vA = *(const float2*)&vt[0][lr][cc][0];
            const float2 vB = *(const float2*)&vt[1][lr][cc][0];
            const float2 vC = *(const float2*)&vt[2][lr][cc][0];
            const float2 vD = *(const float2*)&vt[3][lr][cc][0];
            l += p;
            a0 += p * vA.x;  a1 += p * vA.y;
            a2 += p * vB.x;  a3 += p * vB.y;
            a4 += p * vC.x;  a5 += p * vC.y;
            a6 += p * vD.x;  a7 += p * vD.y;
        }
    }

    // ---- publish partials, merge across halves ----
    pm[half][tt] = mxh;
    pl[half][tt] = l;
    float4 own0 = {a0, a1, a2, a3};
    float4 own1 = {a4, a5, a6, a7};
    *(float4*)&pacc[half][tt][0] = own0;
    *(float4*)&pacc[half][tt][4] = own1;
    __syncthreads();

    const int oth = half ^ 1;
    const float m_o = pm[oth][tt];
    const float l_o = pl[oth][tt];
    const float4 po = (half == 0) ? *(const float4*)&pacc[oth][tt][0]
                                  : *(const float4*)&pacc[oth][tt][4];
    const float4 ow = (half == 0) ? own0 : own1;

    const float M = fmaxf(mxh, m_o);
    const float eo = __expf(mxh - M);
    const float eh = __expf(m_o - M);
    const float inv = 1.f / (l * eo + l_o * eh);

    const int a = sub >> 2, b = sub & 3;
    const int h = hs * 4 + a, w = wsc * 4 + b;
    unsigned short* op = o + (h * 128 + w) * 64 + head * 8 + half * 4;
    float rx = (ow.x * eo + po.x * eh) * inv;
    float ry = (ow.y * eo + po.y * eh) * inv;
    float rz = (ow.z * eo + po.z * eh) * inv;
    float rw = (ow.w * eo + po.w * eh) * inv;
    uint2 packed = {pack2bf(rx, ry), pack2bf(rz, rw)};
    *(uint2*)op = packed;
}

// ---------------- Kernel C: MFMA proj/fc1/fc2 + VALU LayerNorms (r12-verified) ----------------
__global__ __launch_bounds__(256) void k_mlp(
    const float* __restrict__ x, const unsigned short* __restrict__ oatt,
    const unsigned short* __restrict__ pwh, const float* __restrict__ pb,
    const float* __restrict__ g1,
    const float* __restrict__ n2w, const float* __restrict__ n2b,
    const unsigned short* __restrict__ f1h, const float* __restrict__ f1b,
    const float* __restrict__ mnw, const float* __restrict__ mnb,
    const unsigned short* __restrict__ f2h, const float* __restrict__ f2b,
    const float* __restrict__ g2,
    float* __restrict__ out)
{
    __shared__ __align__(16) float xres[CC][ROW];
    __shared__ __align__(16) unsigned short oh[32][72];
    __shared__ __align__(16) unsigned short tbh[32][72];
    __shared__ __align__(16) float h1[HID][ROW];
    __shared__ __align__(16) unsigned short h1h[32][136];
    __shared__ __align__(16) float mu[32], rs[32];

    const int t = threadIdx.x;
    const int pix0 = blockIdx.x * 32;
    const int wv = t >> 6;
    const int l = t & 63;
    const int ln = l & 15;
    const int kg = l >> 4;

    {
        const int c = t >> 2, pxq = (t & 3) * 8;
        *(float4*)&xres[c][pxq]     = *(const float4*)(x + c * HW + pix0 + pxq);
        *(float4*)&xres[c][pxq + 4] = *(const float4*)(x + c * HW + pix0 + pxq + 4);
    }
    #pragma unroll
    for (int pass = 0; pass < 2; ++pass) {
        const int px = (t >> 4) + pass * 16, cg = (t & 15) * 4;
        uint2 ov = *(const uint2*)(oatt + (pix0 + px) * CC + cg);
        *(unsigned*)&oh[px][cg]     = ov.x;
        *(unsigned*)&oh[px][cg + 2] = ov.y;
    }
    __syncthreads();

    {
        f32x4v acc0 = {0.f, 0.f, 0.f, 0.f}, acc1 = {0.f, 0.f, 0.f, 0.f};
        const int m = wv * 16 + ln;
        #pragma unroll
        for (int kk = 0; kk < 64; kk += 32) {
            const int k0 = kk + kg * 8;
            bf16x8 av = *(const bf16x8*)(pwh + m * 64 + k0);
            bf16x8 b0 = *(const bf16x8*)&oh[ln][k0];
            bf16x8 b1 = *(const bf16x8*)&oh[16 + ln][k0];
            acc0 = __builtin_amdgcn_mfma_f32_16x16x32_bf16(av, b0, acc0, 0, 0, 0);
            acc1 = __builtin_amdgcn_mfma_f32_16x16x32_bf16(av, b1, acc1, 0, 0, 0);
        }
        const int r0 = wv * 16 + kg * 4;
        float4 pb4 = *(const float4*)(pb + r0);
        float4 g14 = *(const float4*)(g1 + r0);
        #pragma unroll
        for (int reg = 0; reg < 4; ++reg) {
            const int row = r0 + reg;
            xres[row][ln]      += (&g14.x)[reg] * (acc0[reg] + (&pb4.x)[reg]);
            xres[row][16 + ln] += (&g14.x)[reg] * (acc1[reg] + (&pb4.x)[reg]);
        }
    }
    __syncthreads();

    if (t < 128) {
        const int px = ((t >> 6) << 4) + (t & 15);
        const int part = (t & 63) >> 4;
        float s = 0.f, ss = 0.f;
        #pragma unroll
        for (int i = 0; i < 16; ++i) { float v = xres[part * 16 + i][px]; s += v; ss += v * v; }
        s += __shfl_xor(s, 16); ss += __shfl_xor(ss, 16);
        s += __shfl_xor(s, 32); ss += __shfl_xor(ss, 32);
        if (part == 0) {
            float m = s * (1.f / CC);
            mu[px] = m;
            rs[px] = rsqrtf(ss * (1.f / CC) - m * m + EPSV);
        }
    }
    __syncthreads();

    {
        const int c2 = (t & 31) * 2, px0 = (t >> 5) * 4;
        const float w0 = n2w[c2], b0 = n2b[c2];
        const float w1 = n2w[c2 + 1], b1 = n2b[c2 + 1];
        float4 va = *(float4*)&xres[c2][px0];
        float4 vb = *(float4*)&xres[c2 + 1][px0];
        float4 m4 = *(float4*)&mu[px0];
        float4 r4 = *(float4*)&rs[px0];
        #pragma unroll
        for (int i = 0; i < 4; ++i) {
            float f0 = ((&va.x)[i] - (&m4.x)[i]) * (&r4.x)[i] * w0 + b0;
            float f1 = ((&vb.x)[i] - (&m4.x)[i]) * (&r4.x)[i] * w1 + b1;
            *(unsigned*)&tbh[px0 + i][c2] = pack2bf(f0, f1);
        }
    }
    __syncthreads();

    {
        f32x4v a00 = {0.f,0.f,0.f,0.f}, a01 = {0.f,0.f,0.f,0.f};
        f32x4v a10 = {0.f,0.f,0.f,0.f}, a11 = {0.f,0.f,0.f,0.f};
        const int m0 = wv * 32 + ln;
        #pragma unroll
        for (int kk = 0; kk < 64; kk += 32) {
            const int k0 = kk + kg * 8;
            bf16x8 av0 = *(const bf16x8*)(f1h + m0 * 64 + k0);
            bf16x8 av1 = *(const bf16x8*)(f1h + (m0 + 16) * 64 + k0);
            bf16x8 b0 = *(const bf16x8*)&tbh[ln][k0];
            bf16x8 b1 = *(const bf16x8*)&tbh[16 + ln][k0];
            a00 = __builtin_amdgcn_mfma_f32_16x16x32_bf16(av0, b0, a00, 0, 0, 0);
            a01 = __builtin_amdgcn_mfma_f32_16x16x32_bf16(av0, b1, a01, 0, 0, 0);
            a10 = __builtin_amdgcn_mfma_f32_16x16x32_bf16(av1, b0, a10, 0, 0, 0);
            a11 = __builtin_amdgcn_mfma_f32_16x16x32_bf16(av1, b1, a11, 0, 0, 0);
        }
        const int r0 = wv * 32 + kg * 4;
        float4 fb0 = *(const float4*)(f1b + r0);
        float4 fb1 = *(const float4*)(f1b + r0 + 16);
        #pragma unroll
        for (int reg = 0; reg < 4; ++reg) {
            h1[r0 + reg][ln]           = a00[reg] + (&fb0.x)[reg];
            h1[r0 + reg][16 + ln]      = a01[reg] + (&fb0.x)[reg];
            h1[r0 + 16 + reg][ln]      = a10[reg] + (&fb1.x)[reg];
            h1[r0 + 16 + reg][16 + ln] = a11[reg] + (&fb1.x)[reg];
        }
    }
    __syncthreads();

    if (t < 128) {
        const int px = ((t >> 6) << 4) + (t & 15);
        const int part = (t & 63) >> 4;
        float s = 0.f, ss = 0.f;
        #pragma unroll
        for (int i = 0; i < 32; ++i) { float v = h1[part * 32 + i][px]; s += v; ss += v * v; }
        s += __shfl_xor(s, 16); ss += __shfl_xor(ss, 16);
        s += __shfl_xor(s, 32); ss += __shfl_xor(ss, 32);
        if (part == 0) {
            float m = s * (1.f / HID);
            mu[px] = m;
            rs[px] = rsqrtf(ss * (1.f / HID) - m * m + EPSV);
        }
    }
    __syncthreads();

    {
        const int c2 = (t & 63) * 2, pxm = (t >> 6) * 8;
        const float w0 = mnw[c2], b0 = mnb[c2];
        const float w1 = mnw[c2 + 1], b1 = mnb[c2 + 1];
        #pragma unroll
        for (int qq = 0; qq < 2; ++qq) {
            float4 va = *(float4*)&h1[c2][pxm + qq * 4];
            float4 vb = *(float4*)&h1[c2 + 1][pxm + qq * 4];
            float4 m4 = *(float4*)&mu[pxm + qq * 4];
            float4 r4 = *(float4*)&rs[pxm + qq * 4];
            #pragma unroll
            for (int i = 0; i < 4; ++i) {
                float h0 = ((&va.x)[i] - (&m4.x)[i]) * (&r4.x)[i] * w0 + b0;
                float h1v = ((&vb.x)[i] - (&m4.x)[i]) * (&r4.x)[i] * w1 + b1;
                h0 = h0 / (1.f + __expf(-h0));
                h1v = h1v / (1.f + __expf(-h1v));
                *(unsigned*)&h1h[pxm + qq * 4 + i][c2] = pack2bf(h0, h1v);
            }
        }
    }
    __syncthreads();

    {
        f32x4v acc0 = {0.f, 0.f, 0.f, 0.f}, acc1 = {0.f, 0.f, 0.f, 0.f};
        const int m = wv * 16 + ln;
        #pragma unroll
        for (int kk = 0; kk < 128; kk += 32) {
            const int k0 = kk + kg * 8;
            bf16x8 av = *(const bf16x8*)(f2h + m * 128 + k0);
            bf16x8 b0 = *(const bf16x8*)&h1h[ln][k0];
            bf16x8 b1 = *(const bf16x8*)&h1h[16 + ln][k0];
            acc0 = __builtin_amdgcn_mfma_f32_16x16x32_bf16(av, b0, acc0, 0, 0, 0);
            acc1 = __builtin_amdgcn_mfma_f32_16x16x32_bf16(av, b1, acc1, 0, 0, 0);
        }
        const int r0 = wv * 16 + kg * 4;
        float4 fb4 = *(const float4*)(f2b + r0);
        float4 g24 = *(const float4*)(g2 + r0);
        #pragma unroll
        for (int reg = 0; reg < 4; ++reg) {
            const int row = r0 + reg;
            out[row * HW + pix0 + ln]      = xres[row][ln]
                                           + (&g24.x)[reg] * (acc0[reg] + (&fb4.x)[reg]);
            out[row * HW + pix0 + 16 + ln] = xres[row][16 + ln]
                                           + (&g24.x)[reg] * (acc1[reg] + (&fb4.x)[reg]);
        }
    }
}

extern "C" void kernel_launch(void* const* d_in, const int* in_sizes, int n_in,
                              void* d_out, int out_size, void* d_ws, size_t ws_size,
                              hipStream_t stream) {
    (void)in_sizes; (void)n_in; (void)out_size; (void)ws_size;
    const float* x      = (const float*)d_in[0];
    const float* n1w    = (const float*)d_in[1];
    const float* n1b    = (const float*)d_in[2];
    const float* qkvw   = (const float*)d_in[3];
    const float* qkvb   = (const float*)d_in[4];
    const float* qnw    = (const float*)d_in[5];
    const float* qnb    = (const float*)d_in[6];
    const float* knw    = (const float*)d_in[7];
    const float* knb    = (const float*)d_in[8];
    const float* pw     = (const float*)d_in[9];
    const float* pb     = (const float*)d_in[10];
    const float* g1     = (const float*)d_in[11];
    const float* n2w    = (const float*)d_in[12];
    const float* n2b    = (const float*)d_in[13];
    const float* f1w    = (const float*)d_in[14];
    const float* f1b    = (const float*)d_in[15];
    const float* mnw    = (const float*)d_in[16];
    const float* mnb    = (const float*)d_in[17];
    const float* f2w    = (const float*)d_in[18];
    const float* f2b    = (const float*)d_in[19];
    const float* g2     = (const float*)d_in[20];
    float* out = (float*)d_out;

    float* ws = (float*)d_ws;
    const size_t CHW = (size_t)CC * HW;   // 1,048,576 elements
    unsigned short* wsu = (unsigned short*)ws;
    unsigned short* qo = wsu;                 // bf16, 2 MB
    unsigned short* ko = wsu + CHW;           // bf16, 2 MB
    unsigned short* vo = wsu + 2 * CHW;       // bf16, 2 MB (total 6 MB < 3*CHW floats)
    unsigned short* oatt = (unsigned short*)(ws + 3 * CHW);   // bf16
    unsigned short* wsh = (unsigned short*)(ws + 4 * CHW);
    unsigned short* pwh = wsh;            // 4096
    unsigned short* f1h = wsh + 4096;     // 8192
    unsigned short* f2h = wsh + 12288;    // 8192

    k_ln_qkv<<<dim3(HW / 32), dim3(256), 0, stream>>>(
        x, n1w, n1b, qkvw, qkvb, qnw, qnb, knw, knb, qo, ko, vo);
    k_attn<<<dim3(4, 16, 8), dim3(512), 0, stream>>>(
        qo, ko, vo, oatt, pw, f1w, f2w, pwh, f1h, f2h);
    k_mlp<<<dim3(HW / 32), dim3(256), 0, stream>>>(
        x, oatt, pwh, pb, g1, n2w, n2b, f1h, f1b, mnw, mnb, f2h, f2b, g2, out);
}